// Round 1
// baseline (3530.273 us; speedup 1.0000x reference)
//
#include <hip/hip_runtime.h>

// out[b][f] = sum_{k: rows[k]=f} vals[k] * inputs[b][cols[k]] + bias[f]
//
// Strategy (baseline, round 1): per block, stage TILE_B input rows and
// TILE_B fp32 accumulator rows in LDS; stream the full COO list with
// coalesced loads; scatter via LDS atomicAdd (ds_add_f32). Duplicate COO
// indices sum correctly via atomics. Epilogue: +bias, coalesced float4 store.
//
// LDS budget: 2*4096*4 (in) + 2*4096*4 (acc) = 64 KiB -> 2 blocks/CU,
// 512 thr = 8 waves/block -> 16 waves/CU.

#define NF 4096
#define IND 4096
#define TILE_B 2
#define NTHREADS 512

__global__ __launch_bounds__(NTHREADS, 4)
void spmm_coo_kernel(const float* __restrict__ inputs,
                     const float* __restrict__ vals,
                     const int* __restrict__ rows,
                     const int* __restrict__ cols,
                     const float* __restrict__ bias,
                     float* __restrict__ out,
                     int nnz) {
    __shared__ float in_lds[TILE_B][IND];
    __shared__ float acc[TILE_B][NF];

    const int tid = threadIdx.x;
    const long b0 = (long)blockIdx.x * TILE_B;

    // Stage TILE_B input rows into LDS (coalesced float4) and zero acc.
    for (int i = tid; i < IND / 4; i += NTHREADS) {
#pragma unroll
        for (int j = 0; j < TILE_B; ++j) {
            ((float4*)in_lds[j])[i] =
                ((const float4*)(inputs + (b0 + j) * IND))[i];
            ((float4*)acc[j])[i] = make_float4(0.f, 0.f, 0.f, 0.f);
        }
    }
    __syncthreads();

    // Stream COO entries; coalesced loads of vals/rows/cols.
    // Unrolled x4 for memory-level parallelism on the COO stream.
    int k = tid;
    for (; k + 3 * NTHREADS < nnz; k += 4 * NTHREADS) {
        float v0 = vals[k];
        float v1 = vals[k + NTHREADS];
        float v2 = vals[k + 2 * NTHREADS];
        float v3 = vals[k + 3 * NTHREADS];
        int r0 = rows[k];
        int r1 = rows[k + NTHREADS];
        int r2 = rows[k + 2 * NTHREADS];
        int r3 = rows[k + 3 * NTHREADS];
        int c0 = cols[k];
        int c1 = cols[k + NTHREADS];
        int c2 = cols[k + 2 * NTHREADS];
        int c3 = cols[k + 3 * NTHREADS];
#pragma unroll
        for (int j = 0; j < TILE_B; ++j) {
            atomicAdd(&acc[j][r0], v0 * in_lds[j][c0]);
            atomicAdd(&acc[j][r1], v1 * in_lds[j][c1]);
            atomicAdd(&acc[j][r2], v2 * in_lds[j][c2]);
            atomicAdd(&acc[j][r3], v3 * in_lds[j][c3]);
        }
    }
    for (; k < nnz; k += NTHREADS) {
        float v = vals[k];
        int r = rows[k];
        int c = cols[k];
#pragma unroll
        for (int j = 0; j < TILE_B; ++j) {
            atomicAdd(&acc[j][r], v * in_lds[j][c]);
        }
    }
    __syncthreads();

    // Epilogue: out[b][f] = acc[b][f] + bias[f], coalesced float4.
    for (int i = tid; i < NF / 4; i += NTHREADS) {
        float4 bv = ((const float4*)bias)[i];
#pragma unroll
        for (int j = 0; j < TILE_B; ++j) {
            float4 a = ((float4*)acc[j])[i];
            a.x += bv.x;
            a.y += bv.y;
            a.z += bv.z;
            a.w += bv.w;
            ((float4*)(out + (b0 + j) * NF))[i] = a;
        }
    }
}

extern "C" void kernel_launch(void* const* d_in, const int* in_sizes, int n_in,
                              void* d_out, int out_size, void* d_ws, size_t ws_size,
                              hipStream_t stream) {
    const float* inputs = (const float*)d_in[0];
    const float* vals   = (const float*)d_in[1];
    const int*   rows   = (const int*)d_in[2];
    const int*   cols   = (const int*)d_in[3];
    const float* bias   = (const float*)d_in[4];
    float* out = (float*)d_out;

    const int nnz   = in_sizes[1];
    const int batch = in_sizes[0] / IND;  // 4096
    const int nblocks = batch / TILE_B;   // 2048

    hipLaunchKernelGGL(spmm_coo_kernel, dim3(nblocks), dim3(NTHREADS), 0, stream,
                       inputs, vals, rows, cols, bias, out, nnz);
}

// Round 2
// 2208.396 us; speedup vs baseline: 1.5986x; 1.5986x over previous
//
#include <hip/hip_runtime.h>

// out[b][f] = sum_{k: rows[k]=f} vals[k] * inputs[b][cols[k]] + bias[f]
//
// R2 strategy: build CSR-sorted entry list in d_ws each launch (histogram ->
// single-block scan -> scatter), then main kernel: each block owns TILE_B
// batch rows staged in LDS; each THREAD owns a contiguous chunk of the
// row-sorted entry stream, accumulating per-feature partial sums in
// REGISTERS and flushing via global atomicAdd only when the feature id
// changes (~nnz/41 flushes). Zero LDS atomics. out pre-initialized to bias.

#define NF 4096
#define IND 4096
#define BATCH_TOTAL 4096
#define TILE_B 4
#define NT_MAIN 512

// ---------- K0: out[b][:] = bias ----------
__global__ void init_out_kernel(float* __restrict__ out,
                                const float* __restrict__ bias) {
    const int nf4 = NF / 4;                       // 1024, pow2
    const long total = (long)BATCH_TOTAL * nf4;
    const float4* b4 = (const float4*)bias;
    float4* o4 = (float4*)out;
    for (long i = (long)blockIdx.x * blockDim.x + threadIdx.x; i < total;
         i += (long)gridDim.x * blockDim.x)
        o4[i] = b4[i & (nf4 - 1)];
}

// ---------- K1: histogram of rows ----------
__global__ void hist_kernel(const int* __restrict__ rows,
                            int* __restrict__ cnt, int nnz) {
    int k = blockIdx.x * blockDim.x + threadIdx.x;
    if (k < nnz) atomicAdd(&cnt[rows[k]], 1);
}

// ---------- K2: exclusive scan of 4096 counts -> cursor ----------
__global__ __launch_bounds__(1024)
void scan_kernel(const int* __restrict__ cnt, int* __restrict__ cursor) {
    __shared__ int ts[1024];
    const int t = threadIdx.x;
    const int base = t * 4;
    int e0 = cnt[base], e1 = cnt[base + 1], e2 = cnt[base + 2], e3 = cnt[base + 3];
    int tot = e0 + e1 + e2 + e3;
    ts[t] = tot;
    __syncthreads();
    // Hillis-Steele inclusive scan over 1024 thread-sums
    for (int off = 1; off < 1024; off <<= 1) {
        int v = (t >= off) ? ts[t - off] : 0;
        __syncthreads();
        ts[t] += v;
        __syncthreads();
    }
    int excl = (t == 0) ? 0 : ts[t - 1];
    cursor[base + 0] = excl;
    cursor[base + 1] = excl + e0;
    cursor[base + 2] = excl + e0 + e1;
    cursor[base + 3] = excl + e0 + e1 + e2;
}

// ---------- K3: scatter entries into row-sorted order ----------
__global__ void scatter_kernel(const float* __restrict__ vals,
                               const int* __restrict__ rows,
                               const int* __restrict__ cols,
                               int* __restrict__ cursor,
                               float* __restrict__ sval,
                               int* __restrict__ scol,
                               int* __restrict__ srow, int nnz) {
    int k = blockIdx.x * blockDim.x + threadIdx.x;
    if (k < nnz) {
        int r = rows[k];
        int p = atomicAdd(&cursor[r], 1);
        sval[p] = vals[k];
        scol[p] = cols[k];
        srow[p] = r;
    }
}

// ---------- K4: main SpMM ----------
__global__ __launch_bounds__(NT_MAIN, 4)
void spmm_csr_kernel(const float* __restrict__ inputs,
                     const float* __restrict__ sval,
                     const int* __restrict__ scol,
                     const int* __restrict__ srow,
                     float* __restrict__ out, int nnz) {
    __shared__ float in_lds[TILE_B][IND];   // 64 KiB -> 2 blocks/CU

    const int tid = threadIdx.x;
    const long b0 = (long)blockIdx.x * TILE_B;

    // Stage TILE_B input rows (coalesced float4).
    for (int i = tid; i < IND / 4; i += NT_MAIN) {
#pragma unroll
        for (int j = 0; j < TILE_B; ++j)
            ((float4*)in_lds[j])[i] = ((const float4*)(inputs + (b0 + j) * IND))[i];
    }
    __syncthreads();

    // Each thread: contiguous chunk of the row-sorted entry stream.
    const int C = (nnz + NT_MAIN - 1) / NT_MAIN;   // 328
    int k0 = tid * C;
    int k1 = min(k0 + C, nnz);
    if (k0 < k1) {
        int cur = srow[k0];
        float a0 = 0.f, a1 = 0.f, a2 = 0.f, a3 = 0.f;
        for (int k = k0; k < k1; ++k) {
            int r = srow[k];
            float v = sval[k];
            int c = scol[k];
            if (r != cur) {   // rare: ~1 in 41 iterations per lane
                atomicAdd(&out[(b0 + 0) * NF + cur], a0);
                atomicAdd(&out[(b0 + 1) * NF + cur], a1);
                atomicAdd(&out[(b0 + 2) * NF + cur], a2);
                atomicAdd(&out[(b0 + 3) * NF + cur], a3);
                a0 = a1 = a2 = a3 = 0.f;
                cur = r;
            }
            a0 += v * in_lds[0][c];
            a1 += v * in_lds[1][c];
            a2 += v * in_lds[2][c];
            a3 += v * in_lds[3][c];
        }
        atomicAdd(&out[(b0 + 0) * NF + cur], a0);
        atomicAdd(&out[(b0 + 1) * NF + cur], a1);
        atomicAdd(&out[(b0 + 2) * NF + cur], a2);
        atomicAdd(&out[(b0 + 3) * NF + cur], a3);
    }
}

extern "C" void kernel_launch(void* const* d_in, const int* in_sizes, int n_in,
                              void* d_out, int out_size, void* d_ws, size_t ws_size,
                              hipStream_t stream) {
    const float* inputs = (const float*)d_in[0];
    const float* vals   = (const float*)d_in[1];
    const int*   rows   = (const int*)d_in[2];
    const int*   cols   = (const int*)d_in[3];
    const float* bias   = (const float*)d_in[4];
    float* out = (float*)d_out;
    const int nnz = in_sizes[1];

    // Workspace layout (all 16B-aligned).
    char* ws = (char*)d_ws;
    size_t off = 0;
    int* cnt    = (int*)(ws + off); off += (size_t)NF * 4;            // 16 KB
    int* cursor = (int*)(ws + off); off += (size_t)NF * 4;            // 16 KB
    size_t nnz_b = ((size_t)nnz * 4 + 15) & ~(size_t)15;
    int*   srow = (int*)(ws + off);   off += nnz_b;
    int*   scol = (int*)(ws + off);   off += nnz_b;
    float* sval = (float*)(ws + off); off += nnz_b;

    hipMemsetAsync(cnt, 0, (size_t)NF * 4, stream);

    init_out_kernel<<<2048, 256, 0, stream>>>(out, bias);

    int eb = (nnz + 255) / 256;
    hist_kernel<<<eb, 256, 0, stream>>>(rows, cnt, nnz);
    scan_kernel<<<1, 1024, 0, stream>>>(cnt, cursor);
    scatter_kernel<<<eb, 256, 0, stream>>>(vals, rows, cols, cursor,
                                           sval, scol, srow, nnz);

    spmm_csr_kernel<<<BATCH_TOTAL / TILE_B, NT_MAIN, 0, stream>>>(
        inputs, sval, scol, srow, out, nnz);
}

// Round 3
// 260.931 us; speedup vs baseline: 13.5295x; 8.4635x over previous
//
#include <hip/hip_runtime.h>

// out[b][f] = sum_{k: rows[k]=f} vals[k] * inputs[b][cols[k]] + bias[f]
//
// R3: fully-coalesced CSR-AXPY.
//  K0 hist, K1 scan (rptr+cursor), K2 scatter {col,val} pairs sorted by row,
//  K3 transpose inputs[B][D] -> inT[D][B],
//  K4 main: block = 64 features x 256 batch. Wave walks one feature's entry
//     list ((c,v) wave-uniform scalar loads), acc float4/lane +=
//     v * inT[c][b-slice] (coalesced 1KB/wave). LDS-transposed epilogue
//     writes out+bias coalesced. Zero atomics in the hot loop.
//  XCD-chunked swizzle: blocks sharing a batch-slice co-reside per XCD.
// Fallback to R2 structure if ws_size is too small for inT (needs ~69 MB).

#define NF 4096
#define IND 4096
#define BATCH_TOTAL 4096
#define FT 64          // features per block (main)
#define BT 256         // batch per block (main)
#define NT_MAIN 512

// ---------- K0: histogram of rows ----------
__global__ void hist_kernel(const int* __restrict__ rows,
                            int* __restrict__ cnt, int nnz) {
    int k = blockIdx.x * blockDim.x + threadIdx.x;
    if (k < nnz) atomicAdd(&cnt[rows[k]], 1);
}

// ---------- K1: exclusive scan of 4096 counts -> rptr and cursor ----------
__global__ __launch_bounds__(1024)
void scan_kernel(const int* __restrict__ cnt, int* __restrict__ rptr,
                 int* __restrict__ cursor) {
    __shared__ int ts[1024];
    const int t = threadIdx.x;
    const int base = t * 4;
    int e0 = cnt[base], e1 = cnt[base + 1], e2 = cnt[base + 2], e3 = cnt[base + 3];
    ts[t] = e0 + e1 + e2 + e3;
    __syncthreads();
    for (int off = 1; off < 1024; off <<= 1) {
        int v = (t >= off) ? ts[t - off] : 0;
        __syncthreads();
        ts[t] += v;
        __syncthreads();
    }
    int excl = (t == 0) ? 0 : ts[t - 1];
    int p0 = excl, p1 = excl + e0, p2 = p1 + e1, p3 = p2 + e2;
    rptr[base + 0] = p0;   cursor[base + 0] = p0;
    rptr[base + 1] = p1;   cursor[base + 1] = p1;
    rptr[base + 2] = p2;   cursor[base + 2] = p2;
    rptr[base + 3] = p3;   cursor[base + 3] = p3;
}

// ---------- K2: scatter entries into row-sorted {col, val} pairs ----------
__global__ void scatter_pairs_kernel(const float* __restrict__ vals,
                                     const int* __restrict__ rows,
                                     const int* __restrict__ cols,
                                     int* __restrict__ cursor,
                                     int2* __restrict__ pairs, int nnz) {
    int k = blockIdx.x * blockDim.x + threadIdx.x;
    if (k < nnz) {
        int p = atomicAdd(&cursor[rows[k]], 1);
        pairs[p] = make_int2(cols[k], __float_as_int(vals[k]));
    }
}

// ---------- K3: transpose inputs [B][D] -> inT [D][B] ----------
__global__ __launch_bounds__(256)
void transpose_kernel(const float* __restrict__ in, float* __restrict__ outT) {
    __shared__ float t[64][65];
    const int tb = blockIdx.x;                 // 64x64 tiles, 64 per row
    const int d0 = (tb & 63) * 64;
    const int b0 = (tb >> 6) * 64;
    const int tx4 = threadIdx.x & 15;          // 16 float4 across d
    const int ty  = threadIdx.x >> 4;          // 16 rows of b
#pragma unroll
    for (int p = 0; p < 4; ++p) {
        int brow = ty + p * 16;
        float4 v = *(const float4*)(in + (long)(b0 + brow) * IND + d0 + tx4 * 4);
        t[brow][tx4 * 4 + 0] = v.x;
        t[brow][tx4 * 4 + 1] = v.y;
        t[brow][tx4 * 4 + 2] = v.z;
        t[brow][tx4 * 4 + 3] = v.w;
    }
    __syncthreads();
    const int bx4 = threadIdx.x & 15;          // 16 float4 across b
    const int dy  = threadIdx.x >> 4;          // 16 rows of d
#pragma unroll
    for (int p = 0; p < 4; ++p) {
        int drow = dy + p * 16;
        float4 o;
        o.x = t[bx4 * 4 + 0][drow];
        o.y = t[bx4 * 4 + 1][drow];
        o.z = t[bx4 * 4 + 2][drow];
        o.w = t[bx4 * 4 + 3][drow];
        *(float4*)(outT + (long)(d0 + drow) * BATCH_TOTAL + b0 + bx4 * 4) = o;
    }
}

// ---------- K4: main CSR-AXPY ----------
__global__ __launch_bounds__(NT_MAIN, 2)
void spmm_axpy_kernel(const float* __restrict__ inT,
                      const int2* __restrict__ pairs,
                      const int* __restrict__ rptr,
                      const int* __restrict__ cnt,
                      const float* __restrict__ bias,
                      float* __restrict__ out) {
    __shared__ float tile[FT][BT + 4];         // stride 260 floats (16B-aligned rows)

    // XCD-chunked bijective swizzle: nwg = 1024 (divisible by 8).
    const int bid = blockIdx.x;
    const int per = gridDim.x >> 3;
    const int wg = (bid & 7) * per + (bid >> 3);
    const int bt   = wg >> 6;                  // 0..15 batch tile
    const int fblk = wg & 63;                  // 0..63 feature block
    const int b0 = bt * BT;
    const int fbase = fblk * FT;

    const int wid = threadIdx.x >> 6;          // 0..7
    const int lane = threadIdx.x & 63;

    for (int fi = wid; fi < FT; fi += 8) {
        const int f = fbase + fi;
        const int start = __builtin_amdgcn_readfirstlane(rptr[f]);
        const int n     = __builtin_amdgcn_readfirstlane(cnt[f]);
        float4 acc = make_float4(0.f, 0.f, 0.f, 0.f);
#pragma unroll 4
        for (int k = 0; k < n; ++k) {
            int2 e = pairs[start + k];                     // wave-uniform, 1 line
            float v = __int_as_float(e.y);
            float4 x = *(const float4*)(inT + (long)e.x * BATCH_TOTAL + b0 + lane * 4);
            acc.x += v * x.x;
            acc.y += v * x.y;
            acc.z += v * x.z;
            acc.w += v * x.w;
        }
        *(float4*)(&tile[fi][lane * 4]) = acc;             // contiguous b128, conflict-free
    }
    __syncthreads();

    // Epilogue: out[b0+r][fbase..fbase+63] = tile[.][r] + bias, coalesced.
    const int chunk = threadIdx.x & 15;                    // 16 float4 across f
    const int rbase = threadIdx.x >> 4;                    // 32 rows of b
    float4 bv = ((const float4*)bias)[(fbase >> 2) + chunk];
#pragma unroll
    for (int p = 0; p < 8; ++p) {
        int r = rbase + p * 32;
        float4 o;
        o.x = tile[chunk * 4 + 0][r] + bv.x;
        o.y = tile[chunk * 4 + 1][r] + bv.y;
        o.z = tile[chunk * 4 + 2][r] + bv.z;
        o.w = tile[chunk * 4 + 3][r] + bv.w;
        ((float4*)(out + (long)(b0 + r) * NF + fbase))[chunk] = o;
    }
}

// ---------- Fallback (R2 structure) if ws too small for inT ----------
__global__ void init_out_kernel(float* __restrict__ out,
                                const float* __restrict__ bias) {
    const int nf4 = NF / 4;
    const long total = (long)BATCH_TOTAL * nf4;
    const float4* b4 = (const float4*)bias;
    float4* o4 = (float4*)out;
    for (long i = (long)blockIdx.x * blockDim.x + threadIdx.x; i < total;
         i += (long)gridDim.x * blockDim.x)
        o4[i] = b4[i & (nf4 - 1)];
}

__global__ void scatter3_kernel(const float* __restrict__ vals,
                                const int* __restrict__ rows,
                                const int* __restrict__ cols,
                                int* __restrict__ cursor,
                                float* __restrict__ sval,
                                int* __restrict__ scol,
                                int* __restrict__ srow, int nnz) {
    int k = blockIdx.x * blockDim.x + threadIdx.x;
    if (k < nnz) {
        int r = rows[k];
        int p = atomicAdd(&cursor[r], 1);
        sval[p] = vals[k];
        scol[p] = cols[k];
        srow[p] = r;
    }
}

#define TILE_B_FB 4
__global__ __launch_bounds__(512, 4)
void spmm_csr_fb_kernel(const float* __restrict__ inputs,
                        const float* __restrict__ sval,
                        const int* __restrict__ scol,
                        const int* __restrict__ srow,
                        float* __restrict__ out, int nnz) {
    __shared__ float in_lds[TILE_B_FB][IND];
    const int tid = threadIdx.x;
    const long b0 = (long)blockIdx.x * TILE_B_FB;
    for (int i = tid; i < IND / 4; i += 512) {
#pragma unroll
        for (int j = 0; j < TILE_B_FB; ++j)
            ((float4*)in_lds[j])[i] = ((const float4*)(inputs + (b0 + j) * IND))[i];
    }
    __syncthreads();
    const int C = (nnz + 511) / 512;
    int k0 = tid * C, k1 = min(k0 + C, nnz);
    if (k0 < k1) {
        int cur = srow[k0];
        float a0 = 0.f, a1 = 0.f, a2 = 0.f, a3 = 0.f;
        for (int k = k0; k < k1; ++k) {
            int r = srow[k];
            float v = sval[k];
            int c = scol[k];
            if (r != cur) {
                atomicAdd(&out[(b0 + 0) * NF + cur], a0);
                atomicAdd(&out[(b0 + 1) * NF + cur], a1);
                atomicAdd(&out[(b0 + 2) * NF + cur], a2);
                atomicAdd(&out[(b0 + 3) * NF + cur], a3);
                a0 = a1 = a2 = a3 = 0.f;
                cur = r;
            }
            a0 += v * in_lds[0][c];
            a1 += v * in_lds[1][c];
            a2 += v * in_lds[2][c];
            a3 += v * in_lds[3][c];
        }
        atomicAdd(&out[(b0 + 0) * NF + cur], a0);
        atomicAdd(&out[(b0 + 1) * NF + cur], a1);
        atomicAdd(&out[(b0 + 2) * NF + cur], a2);
        atomicAdd(&out[(b0 + 3) * NF + cur], a3);
    }
}

extern "C" void kernel_launch(void* const* d_in, const int* in_sizes, int n_in,
                              void* d_out, int out_size, void* d_ws, size_t ws_size,
                              hipStream_t stream) {
    const float* inputs = (const float*)d_in[0];
    const float* vals   = (const float*)d_in[1];
    const int*   rows   = (const int*)d_in[2];
    const int*   cols   = (const int*)d_in[3];
    const float* bias   = (const float*)d_in[4];
    float* out = (float*)d_out;
    const int nnz = in_sizes[1];

    char* ws = (char*)d_ws;
    size_t off = 0;
    int* cnt    = (int*)(ws + off); off += (size_t)NF * 4;
    int* cursor = (int*)(ws + off); off += (size_t)NF * 4;
    int* rptr   = (int*)(ws + off); off += (size_t)NF * 4;
    size_t pairs_off = (off + 15) & ~(size_t)15;
    int2* pairs = (int2*)(ws + pairs_off);
    size_t after_pairs = pairs_off + ((size_t)nnz * 8 + 15) & ~(size_t)15;
    float* inT = (float*)(ws + after_pairs);
    size_t need_main = after_pairs + (size_t)IND * BATCH_TOTAL * 4;

    const int eb = (nnz + 255) / 256;

    if (need_main <= ws_size) {
        hipMemsetAsync(cnt, 0, (size_t)NF * 4, stream);
        hist_kernel<<<eb, 256, 0, stream>>>(rows, cnt, nnz);
        scan_kernel<<<1, 1024, 0, stream>>>(cnt, rptr, cursor);
        scatter_pairs_kernel<<<eb, 256, 0, stream>>>(vals, rows, cols, cursor,
                                                     pairs, nnz);
        transpose_kernel<<<(IND / 64) * (BATCH_TOTAL / 64), 256, 0, stream>>>(
            inputs, inT);
        spmm_axpy_kernel<<<(NF / FT) * (BATCH_TOTAL / BT), NT_MAIN, 0, stream>>>(
            inT, pairs, rptr, cnt, bias, out);
    } else {
        // Fallback: R2 structure (needs ~2.1 MB of ws).
        int*   srow = (int*)(ws + pairs_off);
        int*   scol = srow + nnz;
        float* sval = (float*)(scol + nnz);
        hipMemsetAsync(cnt, 0, (size_t)NF * 4, stream);
        init_out_kernel<<<2048, 256, 0, stream>>>(out, bias);
        hist_kernel<<<eb, 256, 0, stream>>>(rows, cnt, nnz);
        scan_kernel<<<1, 1024, 0, stream>>>(cnt, rptr, cursor);
        scatter3_kernel<<<eb, 256, 0, stream>>>(vals, rows, cols, cursor,
                                                sval, scol, srow, nnz);
        spmm_csr_fb_kernel<<<BATCH_TOTAL / TILE_B_FB, 512, 0, stream>>>(
            inputs, sval, scol, srow, out, nnz);
    }
}

// Round 4
// 183.457 us; speedup vs baseline: 19.2430x; 1.4223x over previous
//
#include <hip/hip_runtime.h>

// out[b][f] = sum_{k: rows[k]=f} vals[k] * inputs[b][cols[k]] + bias[f]
//
// R4: R3 structure + bf16 inT (halves gather bytes; 2MB L2 slice/pass) +
// nontemporal out stores (don't evict inT slice from L2) + unroll 8.
//  K0 hist, K1 scan, K2 scatter {col,val} row-sorted pairs,
//  K3 transpose+convert inputs[B][D] f32 -> inT[D][B] bf16,
//  K4 main: block = 64 features x 256 batch; wave walks one feature's
//     entries (scalar pair loads), acc f32x4/lane += v * bf16-gather
//     (coalesced 512B/wave). LDS-transposed epilogue, +bias, nt stores.

#define NF 4096
#define IND 4096
#define BATCH_TOTAL 4096
#define FT 64
#define BT 256
#define NT_MAIN 512

typedef float f32x4 __attribute__((ext_vector_type(4)));

__device__ __forceinline__ float bf2f(unsigned short u) {
    return __uint_as_float(((unsigned int)u) << 16);
}
__device__ __forceinline__ unsigned short f2bf(float x) {
    unsigned int h = __float_as_uint(x);
    h += 0x7fff + ((h >> 16) & 1);   // round-to-nearest-even
    return (unsigned short)(h >> 16);
}

// ---------- K0: histogram of rows ----------
__global__ void hist_kernel(const int* __restrict__ rows,
                            int* __restrict__ cnt, int nnz) {
    int k = blockIdx.x * blockDim.x + threadIdx.x;
    if (k < nnz) atomicAdd(&cnt[rows[k]], 1);
}

// ---------- K1: exclusive scan of 4096 counts -> rptr and cursor ----------
__global__ __launch_bounds__(1024)
void scan_kernel(const int* __restrict__ cnt, int* __restrict__ rptr,
                 int* __restrict__ cursor) {
    __shared__ int ts[1024];
    const int t = threadIdx.x;
    const int base = t * 4;
    int e0 = cnt[base], e1 = cnt[base + 1], e2 = cnt[base + 2], e3 = cnt[base + 3];
    ts[t] = e0 + e1 + e2 + e3;
    __syncthreads();
    for (int off = 1; off < 1024; off <<= 1) {
        int v = (t >= off) ? ts[t - off] : 0;
        __syncthreads();
        ts[t] += v;
        __syncthreads();
    }
    int excl = (t == 0) ? 0 : ts[t - 1];
    int p0 = excl, p1 = excl + e0, p2 = p1 + e1, p3 = p2 + e2;
    rptr[base + 0] = p0;   cursor[base + 0] = p0;
    rptr[base + 1] = p1;   cursor[base + 1] = p1;
    rptr[base + 2] = p2;   cursor[base + 2] = p2;
    rptr[base + 3] = p3;   cursor[base + 3] = p3;
}

// ---------- K2: scatter entries into row-sorted {col, val} pairs ----------
__global__ void scatter_pairs_kernel(const float* __restrict__ vals,
                                     const int* __restrict__ rows,
                                     const int* __restrict__ cols,
                                     int* __restrict__ cursor,
                                     int2* __restrict__ pairs, int nnz) {
    int k = blockIdx.x * blockDim.x + threadIdx.x;
    if (k < nnz) {
        int p = atomicAdd(&cursor[rows[k]], 1);
        pairs[p] = make_int2(cols[k], __float_as_int(vals[k]));
    }
}

// ---------- K3: transpose+convert inputs [B][D] f32 -> inT [D][B] bf16 ----------
__global__ __launch_bounds__(256)
void transpose_kernel(const float* __restrict__ in,
                      unsigned short* __restrict__ outT) {
    __shared__ float t[64][65];
    const int tb = blockIdx.x;                 // 64x64 tiles
    const int d0 = (tb & 63) * 64;
    const int b0 = (tb >> 6) * 64;
    const int tx4 = threadIdx.x & 15;
    const int ty  = threadIdx.x >> 4;
#pragma unroll
    for (int p = 0; p < 4; ++p) {
        int brow = ty + p * 16;
        float4 v = *(const float4*)(in + (long)(b0 + brow) * IND + d0 + tx4 * 4);
        t[brow][tx4 * 4 + 0] = v.x;
        t[brow][tx4 * 4 + 1] = v.y;
        t[brow][tx4 * 4 + 2] = v.z;
        t[brow][tx4 * 4 + 3] = v.w;
    }
    __syncthreads();
    const int bx4 = threadIdx.x & 15;          // ushort4 chunk across b
    const int dy  = threadIdx.x >> 4;
#pragma unroll
    for (int p = 0; p < 4; ++p) {
        int drow = dy + p * 16;
        ushort4 o;
        o.x = f2bf(t[bx4 * 4 + 0][drow]);
        o.y = f2bf(t[bx4 * 4 + 1][drow]);
        o.z = f2bf(t[bx4 * 4 + 2][drow]);
        o.w = f2bf(t[bx4 * 4 + 3][drow]);
        *(ushort4*)(outT + (long)(d0 + drow) * BATCH_TOTAL + b0 + bx4 * 4) = o;
    }
}

// ---------- K4: main CSR-AXPY (bf16 gather) ----------
__global__ __launch_bounds__(NT_MAIN, 2)
void spmm_axpy_kernel(const unsigned short* __restrict__ inT,
                      const int2* __restrict__ pairs,
                      const int* __restrict__ rptr,
                      const int* __restrict__ cnt,
                      const float* __restrict__ bias,
                      float* __restrict__ out) {
    __shared__ float tile[FT][BT + 4];

    // XCD-chunked bijective swizzle (nwg = 1024, divisible by 8); within an
    // XCD chunk, fblk-major so all 64 co-resident blocks share one bt slice.
    const int bid = blockIdx.x;
    const int per = gridDim.x >> 3;
    const int wg = (bid & 7) * per + (bid >> 3);
    const int bt   = wg >> 6;
    const int fblk = wg & 63;
    const int b0 = bt * BT;
    const int fbase = fblk * FT;

    const int wid = threadIdx.x >> 6;
    const int lane = threadIdx.x & 63;

    for (int fi = wid; fi < FT; fi += 8) {
        const int f = fbase + fi;
        const int start = __builtin_amdgcn_readfirstlane(rptr[f]);
        const int n     = __builtin_amdgcn_readfirstlane(cnt[f]);
        float4 acc = make_float4(0.f, 0.f, 0.f, 0.f);
#pragma unroll 8
        for (int k = 0; k < n; ++k) {
            int2 e = pairs[start + k];                         // scalar (uniform)
            float v = __int_as_float(e.y);
            ushort4 u = *(const ushort4*)(inT + (long)e.x * BATCH_TOTAL + b0 + lane * 4);
            acc.x += v * bf2f(u.x);
            acc.y += v * bf2f(u.y);
            acc.z += v * bf2f(u.z);
            acc.w += v * bf2f(u.w);
        }
        *(float4*)(&tile[fi][lane * 4]) = acc;
    }
    __syncthreads();

    // Epilogue: out[b0+r][fbase..fbase+63] = tile[.][r] + bias, coalesced nt.
    const int chunk = threadIdx.x & 15;
    const int rbase = threadIdx.x >> 4;
    float4 bv = ((const float4*)bias)[(fbase >> 2) + chunk];
#pragma unroll
    for (int p = 0; p < 8; ++p) {
        int r = rbase + p * 32;
        f32x4 o;
        o.x = tile[chunk * 4 + 0][r] + bv.x;
        o.y = tile[chunk * 4 + 1][r] + bv.y;
        o.z = tile[chunk * 4 + 2][r] + bv.z;
        o.w = tile[chunk * 4 + 3][r] + bv.w;
        __builtin_nontemporal_store(
            o, (f32x4*)(out + (long)(b0 + r) * NF + fbase + chunk * 4));
    }
}

// ---------- Fallback (R2 structure) if ws too small ----------
__global__ void init_out_kernel(float* __restrict__ out,
                                const float* __restrict__ bias) {
    const int nf4 = NF / 4;
    const long total = (long)BATCH_TOTAL * nf4;
    const float4* b4 = (const float4*)bias;
    float4* o4 = (float4*)out;
    for (long i = (long)blockIdx.x * blockDim.x + threadIdx.x; i < total;
         i += (long)gridDim.x * blockDim.x)
        o4[i] = b4[i & (nf4 - 1)];
}

__global__ void scatter3_kernel(const float* __restrict__ vals,
                                const int* __restrict__ rows,
                                const int* __restrict__ cols,
                                int* __restrict__ cursor,
                                float* __restrict__ sval,
                                int* __restrict__ scol,
                                int* __restrict__ srow, int nnz) {
    int k = blockIdx.x * blockDim.x + threadIdx.x;
    if (k < nnz) {
        int r = rows[k];
        int p = atomicAdd(&cursor[r], 1);
        sval[p] = vals[k];
        scol[p] = cols[k];
        srow[p] = r;
    }
}

#define TILE_B_FB 4
__global__ __launch_bounds__(512, 4)
void spmm_csr_fb_kernel(const float* __restrict__ inputs,
                        const float* __restrict__ sval,
                        const int* __restrict__ scol,
                        const int* __restrict__ srow,
                        float* __restrict__ out, int nnz) {
    __shared__ float in_lds[TILE_B_FB][IND];
    const int tid = threadIdx.x;
    const long b0 = (long)blockIdx.x * TILE_B_FB;
    for (int i = tid; i < IND / 4; i += 512) {
#pragma unroll
        for (int j = 0; j < TILE_B_FB; ++j)
            ((float4*)in_lds[j])[i] = ((const float4*)(inputs + (b0 + j) * IND))[i];
    }
    __syncthreads();
    const int C = (nnz + 511) / 512;
    int k0 = tid * C, k1 = min(k0 + C, nnz);
    if (k0 < k1) {
        int cur = srow[k0];
        float a0 = 0.f, a1 = 0.f, a2 = 0.f, a3 = 0.f;
        for (int k = k0; k < k1; ++k) {
            int r = srow[k];
            float v = sval[k];
            int c = scol[k];
            if (r != cur) {
                atomicAdd(&out[(b0 + 0) * NF + cur], a0);
                atomicAdd(&out[(b0 + 1) * NF + cur], a1);
                atomicAdd(&out[(b0 + 2) * NF + cur], a2);
                atomicAdd(&out[(b0 + 3) * NF + cur], a3);
                a0 = a1 = a2 = a3 = 0.f;
                cur = r;
            }
            a0 += v * in_lds[0][c];
            a1 += v * in_lds[1][c];
            a2 += v * in_lds[2][c];
            a3 += v * in_lds[3][c];
        }
        atomicAdd(&out[(b0 + 0) * NF + cur], a0);
        atomicAdd(&out[(b0 + 1) * NF + cur], a1);
        atomicAdd(&out[(b0 + 2) * NF + cur], a2);
        atomicAdd(&out[(b0 + 3) * NF + cur], a3);
    }
}

extern "C" void kernel_launch(void* const* d_in, const int* in_sizes, int n_in,
                              void* d_out, int out_size, void* d_ws, size_t ws_size,
                              hipStream_t stream) {
    const float* inputs = (const float*)d_in[0];
    const float* vals   = (const float*)d_in[1];
    const int*   rows   = (const int*)d_in[2];
    const int*   cols   = (const int*)d_in[3];
    const float* bias   = (const float*)d_in[4];
    float* out = (float*)d_out;
    const int nnz = in_sizes[1];

    char* ws = (char*)d_ws;
    size_t off = 0;
    int* cnt    = (int*)(ws + off); off += (size_t)NF * 4;
    int* cursor = (int*)(ws + off); off += (size_t)NF * 4;
    int* rptr   = (int*)(ws + off); off += (size_t)NF * 4;
    size_t pairs_off = (off + 15) & ~(size_t)15;
    int2* pairs = (int2*)(ws + pairs_off);
    size_t after_pairs = (pairs_off + (size_t)nnz * 8 + 15) & ~(size_t)15;
    unsigned short* inT = (unsigned short*)(ws + after_pairs);
    size_t need_main = after_pairs + (size_t)IND * BATCH_TOTAL * 2;

    const int eb = (nnz + 255) / 256;

    if (need_main <= ws_size) {
        hipMemsetAsync(cnt, 0, (size_t)NF * 4, stream);
        hist_kernel<<<eb, 256, 0, stream>>>(rows, cnt, nnz);
        scan_kernel<<<1, 1024, 0, stream>>>(cnt, rptr, cursor);
        scatter_pairs_kernel<<<eb, 256, 0, stream>>>(vals, rows, cols, cursor,
                                                     pairs, nnz);
        transpose_kernel<<<(IND / 64) * (BATCH_TOTAL / 64), 256, 0, stream>>>(
            inputs, inT);
        spmm_axpy_kernel<<<(NF / FT) * (BATCH_TOTAL / BT), NT_MAIN, 0, stream>>>(
            inT, pairs, rptr, cnt, bias, out);
    } else {
        int*   srow = (int*)(ws + pairs_off);
        int*   scol = srow + nnz;
        float* sval = (float*)(scol + nnz);
        hipMemsetAsync(cnt, 0, (size_t)NF * 4, stream);
        init_out_kernel<<<2048, 256, 0, stream>>>(out, bias);
        hist_kernel<<<eb, 256, 0, stream>>>(rows, cnt, nnz);
        scan_kernel<<<1, 1024, 0, stream>>>(cnt, rptr, cursor);
        scatter3_kernel<<<eb, 256, 0, stream>>>(vals, rows, cols, cursor,
                                                sval, scol, srow, nnz);
        spmm_csr_fb_kernel<<<BATCH_TOTAL / TILE_B_FB, 512, 0, stream>>>(
            inputs, sval, scol, srow, out, nnz);
    }
}

// Round 5
// 148.647 us; speedup vs baseline: 23.7494x; 1.2342x over previous
//
#include <hip/hip_runtime.h>

// out[b][f] = sum_{k: rows[k]=f} vals[k] * inputs[b][cols[k]] + bias[f]
//
// R5: R4 structure with FT 64->32 (LDS 65->33 KB) => 4 blocks/CU, 32 waves/CU
// to hide L2 gather latency. Single-variable occupancy experiment.
//  K0 hist, K1 scan, K2 scatter {col,val} row-sorted pairs,
//  K3 transpose+convert inputs[B][D] f32 -> inT[D][B] bf16,
//  K4 main: block = 32 features x 256 batch; wave walks a feature's entries
//     (scalar pair loads), acc f32x4/lane += v * bf16-gather (512B/wave,
//     L2-resident). LDS-transposed epilogue, +bias, nontemporal stores.

#define NF 4096
#define IND 4096
#define BATCH_TOTAL 4096
#define FT 32
#define BT 256
#define NT_MAIN 512

typedef float f32x4 __attribute__((ext_vector_type(4)));

__device__ __forceinline__ float bf2f(unsigned short u) {
    return __uint_as_float(((unsigned int)u) << 16);
}
__device__ __forceinline__ unsigned short f2bf(float x) {
    unsigned int h = __float_as_uint(x);
    h += 0x7fff + ((h >> 16) & 1);   // round-to-nearest-even
    return (unsigned short)(h >> 16);
}

// ---------- K0: histogram of rows ----------
__global__ void hist_kernel(const int* __restrict__ rows,
                            int* __restrict__ cnt, int nnz) {
    int k = blockIdx.x * blockDim.x + threadIdx.x;
    if (k < nnz) atomicAdd(&cnt[rows[k]], 1);
}

// ---------- K1: exclusive scan of 4096 counts -> rptr and cursor ----------
__global__ __launch_bounds__(1024)
void scan_kernel(const int* __restrict__ cnt, int* __restrict__ rptr,
                 int* __restrict__ cursor) {
    __shared__ int ts[1024];
    const int t = threadIdx.x;
    const int base = t * 4;
    int e0 = cnt[base], e1 = cnt[base + 1], e2 = cnt[base + 2], e3 = cnt[base + 3];
    ts[t] = e0 + e1 + e2 + e3;
    __syncthreads();
    for (int off = 1; off < 1024; off <<= 1) {
        int v = (t >= off) ? ts[t - off] : 0;
        __syncthreads();
        ts[t] += v;
        __syncthreads();
    }
    int excl = (t == 0) ? 0 : ts[t - 1];
    int p0 = excl, p1 = excl + e0, p2 = p1 + e1, p3 = p2 + e2;
    rptr[base + 0] = p0;   cursor[base + 0] = p0;
    rptr[base + 1] = p1;   cursor[base + 1] = p1;
    rptr[base + 2] = p2;   cursor[base + 2] = p2;
    rptr[base + 3] = p3;   cursor[base + 3] = p3;
}

// ---------- K2: scatter entries into row-sorted {col, val} pairs ----------
__global__ void scatter_pairs_kernel(const float* __restrict__ vals,
                                     const int* __restrict__ rows,
                                     const int* __restrict__ cols,
                                     int* __restrict__ cursor,
                                     int2* __restrict__ pairs, int nnz) {
    int k = blockIdx.x * blockDim.x + threadIdx.x;
    if (k < nnz) {
        int p = atomicAdd(&cursor[rows[k]], 1);
        pairs[p] = make_int2(cols[k], __float_as_int(vals[k]));
    }
}

// ---------- K3: transpose+convert inputs [B][D] f32 -> inT [D][B] bf16 ----------
__global__ __launch_bounds__(256)
void transpose_kernel(const float* __restrict__ in,
                      unsigned short* __restrict__ outT) {
    __shared__ float t[64][65];
    const int tb = blockIdx.x;                 // 64x64 tiles
    const int d0 = (tb & 63) * 64;
    const int b0 = (tb >> 6) * 64;
    const int tx4 = threadIdx.x & 15;
    const int ty  = threadIdx.x >> 4;
#pragma unroll
    for (int p = 0; p < 4; ++p) {
        int brow = ty + p * 16;
        float4 v = *(const float4*)(in + (long)(b0 + brow) * IND + d0 + tx4 * 4);
        t[brow][tx4 * 4 + 0] = v.x;
        t[brow][tx4 * 4 + 1] = v.y;
        t[brow][tx4 * 4 + 2] = v.z;
        t[brow][tx4 * 4 + 3] = v.w;
    }
    __syncthreads();
    const int bx4 = threadIdx.x & 15;          // ushort4 chunk across b
    const int dy  = threadIdx.x >> 4;
#pragma unroll
    for (int p = 0; p < 4; ++p) {
        int drow = dy + p * 16;
        ushort4 o;
        o.x = f2bf(t[bx4 * 4 + 0][drow]);
        o.y = f2bf(t[bx4 * 4 + 1][drow]);
        o.z = f2bf(t[bx4 * 4 + 2][drow]);
        o.w = f2bf(t[bx4 * 4 + 3][drow]);
        *(ushort4*)(outT + (long)(d0 + drow) * BATCH_TOTAL + b0 + bx4 * 4) = o;
    }
}

// ---------- K4: main CSR-AXPY (bf16 gather) ----------
__global__ __launch_bounds__(NT_MAIN, 8)
void spmm_axpy_kernel(const unsigned short* __restrict__ inT,
                      const int2* __restrict__ pairs,
                      const int* __restrict__ rptr,
                      const int* __restrict__ cnt,
                      const float* __restrict__ bias,
                      float* __restrict__ out) {
    __shared__ float tile[FT][BT + 4];   // 32 x 260 x 4B = 33 KB -> 4 blocks/CU

    // XCD-chunked bijective swizzle (nwg = 2048, divisible by 8). fblk is
    // fastest-varying within an XCD chunk so the ~128 co-resident blocks per
    // XCD share one 2MB bt-slice of inT in that XCD's L2.
    const int bid = blockIdx.x;
    const int per = gridDim.x >> 3;            // 256
    const int wg = (bid & 7) * per + (bid >> 3);
    const int fblk = wg & (NF / FT - 1);       // 0..127
    const int bt   = wg >> 7;                  // 0..15
    const int b0 = bt * BT;
    const int fbase = fblk * FT;

    const int wid = threadIdx.x >> 6;          // 0..7
    const int lane = threadIdx.x & 63;

    for (int fi = wid; fi < FT; fi += 8) {     // 4 features per wave
        const int f = fbase + fi;
        const int start = __builtin_amdgcn_readfirstlane(rptr[f]);
        const int n     = __builtin_amdgcn_readfirstlane(cnt[f]);
        float4 acc = make_float4(0.f, 0.f, 0.f, 0.f);
#pragma unroll 8
        for (int k = 0; k < n; ++k) {
            int2 e = pairs[start + k];                         // uniform scalar
            float v = __int_as_float(e.y);
            ushort4 u = *(const ushort4*)(inT + (long)e.x * BATCH_TOTAL + b0 + lane * 4);
            acc.x += v * bf2f(u.x);
            acc.y += v * bf2f(u.y);
            acc.z += v * bf2f(u.z);
            acc.w += v * bf2f(u.w);
        }
        *(float4*)(&tile[fi][lane * 4]) = acc;
    }
    __syncthreads();

    // Epilogue: out[b0+r][fbase..fbase+31] = tile[.][r] + bias, coalesced nt.
    const int chunk = threadIdx.x & 7;         // 8 float4 across f (32 floats)
    const int rbase = threadIdx.x >> 3;        // 64 rows of b
    float4 bv = ((const float4*)bias)[(fbase >> 2) + chunk];
#pragma unroll
    for (int p = 0; p < 4; ++p) {
        int r = rbase + p * 64;
        f32x4 o;
        o.x = tile[chunk * 4 + 0][r] + bv.x;
        o.y = tile[chunk * 4 + 1][r] + bv.y;
        o.z = tile[chunk * 4 + 2][r] + bv.z;
        o.w = tile[chunk * 4 + 3][r] + bv.w;
        __builtin_nontemporal_store(
            o, (f32x4*)(out + (long)(b0 + r) * NF + fbase + chunk * 4));
    }
}

// ---------- Fallback (R2 structure) if ws too small ----------
__global__ void init_out_kernel(float* __restrict__ out,
                                const float* __restrict__ bias) {
    const int nf4 = NF / 4;
    const long total = (long)BATCH_TOTAL * nf4;
    const float4* b4 = (const float4*)bias;
    float4* o4 = (float4*)out;
    for (long i = (long)blockIdx.x * blockDim.x + threadIdx.x; i < total;
         i += (long)gridDim.x * blockDim.x)
        o4[i] = b4[i & (nf4 - 1)];
}

__global__ void scatter3_kernel(const float* __restrict__ vals,
                                const int* __restrict__ rows,
                                const int* __restrict__ cols,
                                int* __restrict__ cursor,
                                float* __restrict__ sval,
                                int* __restrict__ scol,
                                int* __restrict__ srow, int nnz) {
    int k = blockIdx.x * blockDim.x + threadIdx.x;
    if (k < nnz) {
        int r = rows[k];
        int p = atomicAdd(&cursor[r], 1);
        sval[p] = vals[k];
        scol[p] = cols[k];
        srow[p] = r;
    }
}

#define TILE_B_FB 4
__global__ __launch_bounds__(512, 4)
void spmm_csr_fb_kernel(const float* __restrict__ inputs,
                        const float* __restrict__ sval,
                        const int* __restrict__ scol,
                        const int* __restrict__ srow,
                        float* __restrict__ out, int nnz) {
    __shared__ float in_lds[TILE_B_FB][IND];
    const int tid = threadIdx.x;
    const long b0 = (long)blockIdx.x * TILE_B_FB;
    for (int i = tid; i < IND / 4; i += 512) {
#pragma unroll
        for (int j = 0; j < TILE_B_FB; ++j)
            ((float4*)in_lds[j])[i] = ((const float4*)(inputs + (b0 + j) * IND))[i];
    }
    __syncthreads();
    const int C = (nnz + 511) / 512;
    int k0 = tid * C, k1 = min(k0 + C, nnz);
    if (k0 < k1) {
        int cur = srow[k0];
        float a0 = 0.f, a1 = 0.f, a2 = 0.f, a3 = 0.f;
        for (int k = k0; k < k1; ++k) {
            int r = srow[k];
            float v = sval[k];
            int c = scol[k];
            if (r != cur) {
                atomicAdd(&out[(b0 + 0) * NF + cur], a0);
                atomicAdd(&out[(b0 + 1) * NF + cur], a1);
                atomicAdd(&out[(b0 + 2) * NF + cur], a2);
                atomicAdd(&out[(b0 + 3) * NF + cur], a3);
                a0 = a1 = a2 = a3 = 0.f;
                cur = r;
            }
            a0 += v * in_lds[0][c];
            a1 += v * in_lds[1][c];
            a2 += v * in_lds[2][c];
            a3 += v * in_lds[3][c];
        }
        atomicAdd(&out[(b0 + 0) * NF + cur], a0);
        atomicAdd(&out[(b0 + 1) * NF + cur], a1);
        atomicAdd(&out[(b0 + 2) * NF + cur], a2);
        atomicAdd(&out[(b0 + 3) * NF + cur], a3);
    }
}

extern "C" void kernel_launch(void* const* d_in, const int* in_sizes, int n_in,
                              void* d_out, int out_size, void* d_ws, size_t ws_size,
                              hipStream_t stream) {
    const float* inputs = (const float*)d_in[0];
    const float* vals   = (const float*)d_in[1];
    const int*   rows   = (const int*)d_in[2];
    const int*   cols   = (const int*)d_in[3];
    const float* bias   = (const float*)d_in[4];
    float* out = (float*)d_out;
    const int nnz = in_sizes[1];

    char* ws = (char*)d_ws;
    size_t off = 0;
    int* cnt    = (int*)(ws + off); off += (size_t)NF * 4;
    int* cursor = (int*)(ws + off); off += (size_t)NF * 4;
    int* rptr   = (int*)(ws + off); off += (size_t)NF * 4;
    size_t pairs_off = (off + 15) & ~(size_t)15;
    int2* pairs = (int2*)(ws + pairs_off);
    size_t after_pairs = (pairs_off + (size_t)nnz * 8 + 15) & ~(size_t)15;
    unsigned short* inT = (unsigned short*)(ws + after_pairs);
    size_t need_main = after_pairs + (size_t)IND * BATCH_TOTAL * 2;

    const int eb = (nnz + 255) / 256;

    if (need_main <= ws_size) {
        hipMemsetAsync(cnt, 0, (size_t)NF * 4, stream);
        hist_kernel<<<eb, 256, 0, stream>>>(rows, cnt, nnz);
        scan_kernel<<<1, 1024, 0, stream>>>(cnt, rptr, cursor);
        scatter_pairs_kernel<<<eb, 256, 0, stream>>>(vals, rows, cols, cursor,
                                                     pairs, nnz);
        transpose_kernel<<<(IND / 64) * (BATCH_TOTAL / 64), 256, 0, stream>>>(
            inputs, inT);
        spmm_axpy_kernel<<<(NF / FT) * (BATCH_TOTAL / BT), NT_MAIN, 0, stream>>>(
            inT, pairs, rptr, cnt, bias, out);
    } else {
        int*   srow = (int*)(ws + pairs_off);
        int*   scol = srow + nnz;
        float* sval = (float*)(scol + nnz);
        hipMemsetAsync(cnt, 0, (size_t)NF * 4, stream);
        init_out_kernel<<<2048, 256, 0, stream>>>(out, bias);
        hist_kernel<<<eb, 256, 0, stream>>>(rows, cnt, nnz);
        scan_kernel<<<1, 1024, 0, stream>>>(cnt, rptr, cursor);
        scatter3_kernel<<<eb, 256, 0, stream>>>(vals, rows, cols, cursor,
                                                sval, scol, srow, nnz);
        spmm_csr_fb_kernel<<<BATCH_TOTAL / TILE_B_FB, 512, 0, stream>>>(
            inputs, sval, scol, srow, out, nnz);
    }
}

// Round 6
// 147.763 us; speedup vs baseline: 23.8915x; 1.0060x over previous
//
#include <hip/hip_runtime.h>

// out[b][f] = sum_{k: rows[k]=f} vals[k] * inputs[b][cols[k]] + bias[f]
//
// R6: R5 + (a) block's pair-list staged in LDS (kills scalar-cache miss
// serialization on the uniform entry stream), (b) bf16 accumulator tile in
// LDS so total LDS stays ~31 KB -> 4 blocks/CU (32 waves, max occupancy).
//  K0 hist, K1 scan, K2 scatter {col,val} row-sorted pairs,
//  K3 transpose+convert inputs[B][D] f32 -> inT[D][B] bf16,
//  K4 main: block = 32 features x 256 batch; stage pairs -> LDS; wave walks
//     a feature's entries (ds_read_b64 broadcast), acc f32x4/lane +=
//     v * bf16-gather (512B/wave, L2-resident). bf16 LDS transpose epilogue,
//     +bias (f32), nontemporal stores.

#define NF 4096
#define IND 4096
#define BATCH_TOTAL 4096
#define FT 32
#define BT 256
#define NT_MAIN 512
#define PAIR_CAP 1792   // mean block entries ~1312 (sigma ~36); 14.3 KB

typedef float f32x4 __attribute__((ext_vector_type(4)));

__device__ __forceinline__ float bf2f(unsigned short u) {
    return __uint_as_float(((unsigned int)u) << 16);
}
__device__ __forceinline__ unsigned short f2bf(float x) {
    unsigned int h = __float_as_uint(x);
    h += 0x7fff + ((h >> 16) & 1);   // round-to-nearest-even
    return (unsigned short)(h >> 16);
}

// ---------- K0: histogram of rows ----------
__global__ void hist_kernel(const int* __restrict__ rows,
                            int* __restrict__ cnt, int nnz) {
    int k = blockIdx.x * blockDim.x + threadIdx.x;
    if (k < nnz) atomicAdd(&cnt[rows[k]], 1);
}

// ---------- K1: exclusive scan of 4096 counts -> rptr and cursor ----------
__global__ __launch_bounds__(1024)
void scan_kernel(const int* __restrict__ cnt, int* __restrict__ rptr,
                 int* __restrict__ cursor) {
    __shared__ int ts[1024];
    const int t = threadIdx.x;
    const int base = t * 4;
    int e0 = cnt[base], e1 = cnt[base + 1], e2 = cnt[base + 2], e3 = cnt[base + 3];
    ts[t] = e0 + e1 + e2 + e3;
    __syncthreads();
    for (int off = 1; off < 1024; off <<= 1) {
        int v = (t >= off) ? ts[t - off] : 0;
        __syncthreads();
        ts[t] += v;
        __syncthreads();
    }
    int excl = (t == 0) ? 0 : ts[t - 1];
    int p0 = excl, p1 = excl + e0, p2 = p1 + e1, p3 = p2 + e2;
    rptr[base + 0] = p0;   cursor[base + 0] = p0;
    rptr[base + 1] = p1;   cursor[base + 1] = p1;
    rptr[base + 2] = p2;   cursor[base + 2] = p2;
    rptr[base + 3] = p3;   cursor[base + 3] = p3;
}

// ---------- K2: scatter entries into row-sorted {col, val} pairs ----------
__global__ void scatter_pairs_kernel(const float* __restrict__ vals,
                                     const int* __restrict__ rows,
                                     const int* __restrict__ cols,
                                     int* __restrict__ cursor,
                                     int2* __restrict__ pairs, int nnz) {
    int k = blockIdx.x * blockDim.x + threadIdx.x;
    if (k < nnz) {
        int p = atomicAdd(&cursor[rows[k]], 1);
        pairs[p] = make_int2(cols[k], __float_as_int(vals[k]));
    }
}

// ---------- K3: transpose+convert inputs [B][D] f32 -> inT [D][B] bf16 ----------
__global__ __launch_bounds__(256)
void transpose_kernel(const float* __restrict__ in,
                      unsigned short* __restrict__ outT) {
    __shared__ float t[64][65];
    const int tb = blockIdx.x;                 // 64x64 tiles
    const int d0 = (tb & 63) * 64;
    const int b0 = (tb >> 6) * 64;
    const int tx4 = threadIdx.x & 15;
    const int ty  = threadIdx.x >> 4;
#pragma unroll
    for (int p = 0; p < 4; ++p) {
        int brow = ty + p * 16;
        float4 v = *(const float4*)(in + (long)(b0 + brow) * IND + d0 + tx4 * 4);
        t[brow][tx4 * 4 + 0] = v.x;
        t[brow][tx4 * 4 + 1] = v.y;
        t[brow][tx4 * 4 + 2] = v.z;
        t[brow][tx4 * 4 + 3] = v.w;
    }
    __syncthreads();
    const int bx4 = threadIdx.x & 15;
    const int dy  = threadIdx.x >> 4;
#pragma unroll
    for (int p = 0; p < 4; ++p) {
        int drow = dy + p * 16;
        ushort4 o;
        o.x = f2bf(t[bx4 * 4 + 0][drow]);
        o.y = f2bf(t[bx4 * 4 + 1][drow]);
        o.z = f2bf(t[bx4 * 4 + 2][drow]);
        o.w = f2bf(t[bx4 * 4 + 3][drow]);
        *(ushort4*)(outT + (long)(d0 + drow) * BATCH_TOTAL + b0 + bx4 * 4) = o;
    }
}

// ---------- K4: main CSR-AXPY (bf16 gather, LDS pair list) ----------
__global__ __launch_bounds__(NT_MAIN, 8)
void spmm_axpy_kernel(const unsigned short* __restrict__ inT,
                      const int2* __restrict__ pairs,
                      const int* __restrict__ rptr,
                      const int* __restrict__ cnt,
                      const float* __restrict__ bias,
                      float* __restrict__ out) {
    __shared__ unsigned short tile[FT][BT + 8];  // 16.9 KB (bf16 acc tile)
    __shared__ int2 pl[PAIR_CAP];                // 14.3 KB pair stage

    // XCD-chunked bijective swizzle (nwg = 2048); fblk fastest within a
    // chunk so co-resident blocks per XCD share a 2MB bt-slice of inT.
    const int bid = blockIdx.x;
    const int per = gridDim.x >> 3;            // 256
    const int wg = (bid & 7) * per + (bid >> 3);
    const int fblk = wg & (NF / FT - 1);       // 0..127
    const int bt   = wg >> 7;                  // 0..15
    const int b0 = bt * BT;
    const int fbase = fblk * FT;

    const int tid = threadIdx.x;
    const int wid = tid >> 6;                  // 0..7
    const int lane = tid & 63;

    // Stage this block's pair range [rptr[fbase], rptr[fbase+FT-1]+cnt).
    const int base = __builtin_amdgcn_readfirstlane(rptr[fbase]);
    const int endv = __builtin_amdgcn_readfirstlane(
        rptr[fbase + FT - 1] + cnt[fbase + FT - 1]);
    const int total = endv - base;
    const bool staged = (total <= PAIR_CAP);
    if (staged) {
        for (int i = tid; i < total; i += NT_MAIN) pl[i] = pairs[base + i];
    }
    __syncthreads();

    for (int fi = wid; fi < FT; fi += 8) {     // 4 features per wave
        const int f = fbase + fi;
        const int start = __builtin_amdgcn_readfirstlane(rptr[f]);
        const int n     = __builtin_amdgcn_readfirstlane(cnt[f]);
        float4 acc = make_float4(0.f, 0.f, 0.f, 0.f);
        if (staged) {
            const int o = start - base;
#pragma unroll 8
            for (int k = 0; k < n; ++k) {
                int2 e = pl[o + k];                            // ds broadcast
                float v = __int_as_float(e.y);
                uint2 u = *(const uint2*)(inT + (long)e.x * BATCH_TOTAL + b0 + lane * 4);
                acc.x += v * __uint_as_float(u.x << 16);
                acc.y += v * __uint_as_float(u.x & 0xffff0000u);
                acc.z += v * __uint_as_float(u.y << 16);
                acc.w += v * __uint_as_float(u.y & 0xffff0000u);
            }
        } else {
#pragma unroll 8
            for (int k = 0; k < n; ++k) {
                int2 e = pairs[start + k];
                float v = __int_as_float(e.y);
                uint2 u = *(const uint2*)(inT + (long)e.x * BATCH_TOTAL + b0 + lane * 4);
                acc.x += v * __uint_as_float(u.x << 16);
                acc.y += v * __uint_as_float(u.x & 0xffff0000u);
                acc.z += v * __uint_as_float(u.y << 16);
                acc.w += v * __uint_as_float(u.y & 0xffff0000u);
            }
        }
        ushort4 packed;
        packed.x = f2bf(acc.x);
        packed.y = f2bf(acc.y);
        packed.z = f2bf(acc.z);
        packed.w = f2bf(acc.w);
        *(ushort4*)(&tile[fi][lane * 4]) = packed;             // contiguous b64
    }
    __syncthreads();

    // Epilogue: out[b0+r][fbase..fbase+31] = tile[.][r] + bias, coalesced nt.
    const int chunk = tid & 7;                 // 8 f32x4 across 32 f
    const int rbase = tid >> 3;                // 64 rows of b
    float4 bv = ((const float4*)bias)[(fbase >> 2) + chunk];
#pragma unroll
    for (int p = 0; p < 4; ++p) {
        int r = rbase + p * 64;
        f32x4 o;
        o.x = bf2f(tile[chunk * 4 + 0][r]) + bv.x;
        o.y = bf2f(tile[chunk * 4 + 1][r]) + bv.y;
        o.z = bf2f(tile[chunk * 4 + 2][r]) + bv.z;
        o.w = bf2f(tile[chunk * 4 + 3][r]) + bv.w;
        __builtin_nontemporal_store(
            o, (f32x4*)(out + (long)(b0 + r) * NF + fbase + chunk * 4));
    }
}

// ---------- Fallback (R2 structure) if ws too small ----------
__global__ void init_out_kernel(float* __restrict__ out,
                                const float* __restrict__ bias) {
    const int nf4 = NF / 4;
    const long total = (long)BATCH_TOTAL * nf4;
    const float4* b4 = (const float4*)bias;
    float4* o4 = (float4*)out;
    for (long i = (long)blockIdx.x * blockDim.x + threadIdx.x; i < total;
         i += (long)gridDim.x * blockDim.x)
        o4[i] = b4[i & (nf4 - 1)];
}

__global__ void scatter3_kernel(const float* __restrict__ vals,
                                const int* __restrict__ rows,
                                const int* __restrict__ cols,
                                int* __restrict__ cursor,
                                float* __restrict__ sval,
                                int* __restrict__ scol,
                                int* __restrict__ srow, int nnz) {
    int k = blockIdx.x * blockDim.x + threadIdx.x;
    if (k < nnz) {
        int r = rows[k];
        int p = atomicAdd(&cursor[r], 1);
        sval[p] = vals[k];
        scol[p] = cols[k];
        srow[p] = r;
    }
}

#define TILE_B_FB 4
__global__ __launch_bounds__(512, 4)
void spmm_csr_fb_kernel(const float* __restrict__ inputs,
                        const float* __restrict__ sval,
                        const int* __restrict__ scol,
                        const int* __restrict__ srow,
                        float* __restrict__ out, int nnz) {
    __shared__ float in_lds[TILE_B_FB][IND];
    const int tid = threadIdx.x;
    const long b0 = (long)blockIdx.x * TILE_B_FB;
    for (int i = tid; i < IND / 4; i += 512) {
#pragma unroll
        for (int j = 0; j < TILE_B_FB; ++j)
            ((float4*)in_lds[j])[i] = ((const float4*)(inputs + (b0 + j) * IND))[i];
    }
    __syncthreads();
    const int C = (nnz + 511) / 512;
    int k0 = tid * C, k1 = min(k0 + C, nnz);
    if (k0 < k1) {
        int cur = srow[k0];
        float a0 = 0.f, a1 = 0.f, a2 = 0.f, a3 = 0.f;
        for (int k = k0; k < k1; ++k) {
            int r = srow[k];
            float v = sval[k];
            int c = scol[k];
            if (r != cur) {
                atomicAdd(&out[(b0 + 0) * NF + cur], a0);
                atomicAdd(&out[(b0 + 1) * NF + cur], a1);
                atomicAdd(&out[(b0 + 2) * NF + cur], a2);
                atomicAdd(&out[(b0 + 3) * NF + cur], a3);
                a0 = a1 = a2 = a3 = 0.f;
                cur = r;
            }
            a0 += v * in_lds[0][c];
            a1 += v * in_lds[1][c];
            a2 += v * in_lds[2][c];
            a3 += v * in_lds[3][c];
        }
        atomicAdd(&out[(b0 + 0) * NF + cur], a0);
        atomicAdd(&out[(b0 + 1) * NF + cur], a1);
        atomicAdd(&out[(b0 + 2) * NF + cur], a2);
        atomicAdd(&out[(b0 + 3) * NF + cur], a3);
    }
}

extern "C" void kernel_launch(void* const* d_in, const int* in_sizes, int n_in,
                              void* d_out, int out_size, void* d_ws, size_t ws_size,
                              hipStream_t stream) {
    const float* inputs = (const float*)d_in[0];
    const float* vals   = (const float*)d_in[1];
    const int*   rows   = (const int*)d_in[2];
    const int*   cols   = (const int*)d_in[3];
    const float* bias   = (const float*)d_in[4];
    float* out = (float*)d_out;
    const int nnz = in_sizes[1];

    char* ws = (char*)d_ws;
    size_t off = 0;
    int* cnt    = (int*)(ws + off); off += (size_t)NF * 4;
    int* cursor = (int*)(ws + off); off += (size_t)NF * 4;
    int* rptr   = (int*)(ws + off); off += (size_t)NF * 4;
    size_t pairs_off = (off + 15) & ~(size_t)15;
    int2* pairs = (int2*)(ws + pairs_off);
    size_t after_pairs = (pairs_off + (size_t)nnz * 8 + 15) & ~(size_t)15;
    unsigned short* inT = (unsigned short*)(ws + after_pairs);
    size_t need_main = after_pairs + (size_t)IND * BATCH_TOTAL * 2;

    const int eb = (nnz + 255) / 256;

    if (need_main <= ws_size) {
        hipMemsetAsync(cnt, 0, (size_t)NF * 4, stream);
        hist_kernel<<<eb, 256, 0, stream>>>(rows, cnt, nnz);
        scan_kernel<<<1, 1024, 0, stream>>>(cnt, rptr, cursor);
        scatter_pairs_kernel<<<eb, 256, 0, stream>>>(vals, rows, cols, cursor,
                                                     pairs, nnz);
        transpose_kernel<<<(IND / 64) * (BATCH_TOTAL / 64), 256, 0, stream>>>(
            inputs, inT);
        spmm_axpy_kernel<<<(NF / FT) * (BATCH_TOTAL / BT), NT_MAIN, 0, stream>>>(
            inT, pairs, rptr, cnt, bias, out);
    } else {
        int*   srow = (int*)(ws + pairs_off);
        int*   scol = srow + nnz;
        float* sval = (float*)(scol + nnz);
        hipMemsetAsync(cnt, 0, (size_t)NF * 4, stream);
        init_out_kernel<<<2048, 256, 0, stream>>>(out, bias);
        hist_kernel<<<eb, 256, 0, stream>>>(rows, cnt, nnz);
        scan_kernel<<<1, 1024, 0, stream>>>(cnt, rptr, cursor);
        scatter3_kernel<<<eb, 256, 0, stream>>>(vals, rows, cols, cursor,
                                                sval, scol, srow, nnz);
        spmm_csr_fb_kernel<<<BATCH_TOTAL / TILE_B_FB, 512, 0, stream>>>(
            inputs, sval, scol, srow, out, nnz);
    }
}

// Round 8
// 137.913 us; speedup vs baseline: 25.5978x; 1.0714x over previous
//
#include <hip/hip_runtime.h>

// out[b][f] = sum_{k: rows[k]=f} vals[k] * inputs[b][cols[k]] + bias[f]
//
// R7b (compile fix of R7): AXPY main loop rebuilt for instruction economy:
//  - BT 256->512: 16B/lane (dwordx4, 8 bf16) gathers; entry-visits halve.
//  - packed f32x2 accumulate (v_pk_fma_f32 candidate), fp contract fast
//    (pragma at start of kernel compound statement — legal position).
//  - pairs-LDS stage dropped (R6 proved it neutral); uniform scalar loads.
//  - bf16 acc tile [32][520] = 33.3 KB -> 4 blocks/CU, 32 waves.
//  - grid 1024 = 128 fblk x 8 bt; XCD chunk = one 2MB bt-slice of inT.
// Setup unchanged: hist, scan, scatter pairs, transpose->bf16 inT.

#define NF 4096
#define IND 4096
#define BATCH_TOTAL 4096
#define FT 32
#define BT 512
#define NT_MAIN 512

typedef float f32x4 __attribute__((ext_vector_type(4)));
typedef float f32x2 __attribute__((ext_vector_type(2)));

__device__ __forceinline__ float bf2f(unsigned short u) {
    return __uint_as_float(((unsigned int)u) << 16);
}
__device__ __forceinline__ unsigned short f2bf(float x) {
    unsigned int h = __float_as_uint(x);
    h += 0x7fff + ((h >> 16) & 1);   // round-to-nearest-even
    return (unsigned short)(h >> 16);
}

// ---------- K0: histogram of rows ----------
__global__ void hist_kernel(const int* __restrict__ rows,
                            int* __restrict__ cnt, int nnz) {
    int k = blockIdx.x * blockDim.x + threadIdx.x;
    if (k < nnz) atomicAdd(&cnt[rows[k]], 1);
}

// ---------- K1: exclusive scan of 4096 counts -> rptr and cursor ----------
__global__ __launch_bounds__(1024)
void scan_kernel(const int* __restrict__ cnt, int* __restrict__ rptr,
                 int* __restrict__ cursor) {
    __shared__ int ts[1024];
    const int t = threadIdx.x;
    const int base = t * 4;
    int e0 = cnt[base], e1 = cnt[base + 1], e2 = cnt[base + 2], e3 = cnt[base + 3];
    ts[t] = e0 + e1 + e2 + e3;
    __syncthreads();
    for (int off = 1; off < 1024; off <<= 1) {
        int v = (t >= off) ? ts[t - off] : 0;
        __syncthreads();
        ts[t] += v;
        __syncthreads();
    }
    int excl = (t == 0) ? 0 : ts[t - 1];
    int p0 = excl, p1 = excl + e0, p2 = p1 + e1, p3 = p2 + e2;
    rptr[base + 0] = p0;   cursor[base + 0] = p0;
    rptr[base + 1] = p1;   cursor[base + 1] = p1;
    rptr[base + 2] = p2;   cursor[base + 2] = p2;
    rptr[base + 3] = p3;   cursor[base + 3] = p3;
}

// ---------- K2: scatter entries into row-sorted {col, val} pairs ----------
__global__ void scatter_pairs_kernel(const float* __restrict__ vals,
                                     const int* __restrict__ rows,
                                     const int* __restrict__ cols,
                                     int* __restrict__ cursor,
                                     int2* __restrict__ pairs, int nnz) {
    int k = blockIdx.x * blockDim.x + threadIdx.x;
    if (k < nnz) {
        int p = atomicAdd(&cursor[rows[k]], 1);
        pairs[p] = make_int2(cols[k], __float_as_int(vals[k]));
    }
}

// ---------- K3: transpose+convert inputs [B][D] f32 -> inT [D][B] bf16 ----------
__global__ __launch_bounds__(256)
void transpose_kernel(const float* __restrict__ in,
                      unsigned short* __restrict__ outT) {
    __shared__ float t[64][65];
    const int tb = blockIdx.x;                 // 64x64 tiles
    const int d0 = (tb & 63) * 64;
    const int b0 = (tb >> 6) * 64;
    const int tx4 = threadIdx.x & 15;
    const int ty  = threadIdx.x >> 4;
#pragma unroll
    for (int p = 0; p < 4; ++p) {
        int brow = ty + p * 16;
        float4 v = *(const float4*)(in + (long)(b0 + brow) * IND + d0 + tx4 * 4);
        t[brow][tx4 * 4 + 0] = v.x;
        t[brow][tx4 * 4 + 1] = v.y;
        t[brow][tx4 * 4 + 2] = v.z;
        t[brow][tx4 * 4 + 3] = v.w;
    }
    __syncthreads();
    const int bx4 = threadIdx.x & 15;
    const int dy  = threadIdx.x >> 4;
#pragma unroll
    for (int p = 0; p < 4; ++p) {
        int drow = dy + p * 16;
        ushort4 o;
        o.x = f2bf(t[bx4 * 4 + 0][drow]);
        o.y = f2bf(t[bx4 * 4 + 1][drow]);
        o.z = f2bf(t[bx4 * 4 + 2][drow]);
        o.w = f2bf(t[bx4 * 4 + 3][drow]);
        *(ushort4*)(outT + (long)(d0 + drow) * BATCH_TOTAL + b0 + bx4 * 4) = o;
    }
}

// ---------- K4: main CSR-AXPY (bf16 dwordx4 gather, packed f32x2 math) ----------
__global__ __launch_bounds__(NT_MAIN, 8)
void spmm_axpy_kernel(const unsigned short* __restrict__ inT,
                      const int2* __restrict__ pairs,
                      const int* __restrict__ rptr,
                      const int* __restrict__ cnt,
                      const float* __restrict__ bias,
                      float* __restrict__ out) {
#pragma clang fp contract(fast)
    __shared__ unsigned short tile[FT][BT + 8];  // 33.3 KB -> 4 blocks/CU

    // XCD-chunked bijective swizzle (nwg = 1024). fblk fastest within a
    // chunk: each XCD's 128 blocks sweep all fblks of ONE 2MB bt-slice.
    const int bid = blockIdx.x;
    const int per = gridDim.x >> 3;            // 128
    const int wg = (bid & 7) * per + (bid >> 3);
    const int fblk = wg & (NF / FT - 1);       // 0..127
    const int bt   = wg >> 7;                  // 0..7
    const int b0 = bt * BT;
    const int fbase = fblk * FT;

    const int tid = threadIdx.x;
    const int wid = tid >> 6;                  // 0..7
    const int lane = tid & 63;

    for (int fi = wid; fi < FT; fi += 8) {     // 4 features per wave
        const int f = fbase + fi;
        const int start = __builtin_amdgcn_readfirstlane(rptr[f]);
        const int n     = __builtin_amdgcn_readfirstlane(cnt[f]);
        f32x2 a0 = {0.f, 0.f}, a1 = {0.f, 0.f}, a2 = {0.f, 0.f}, a3 = {0.f, 0.f};
        const unsigned short* gbase = inT + b0 + lane * 8;
#pragma unroll 4
        for (int k = 0; k < n; ++k) {
            int2 e = pairs[start + k];                         // uniform scalar
            float v = __int_as_float(e.y);
            f32x2 vv = {v, v};
            uint4 u = *(const uint4*)(gbase + (long)e.x * BATCH_TOTAL);
            f32x2 x0 = {__uint_as_float(u.x << 16), __uint_as_float(u.x & 0xffff0000u)};
            f32x2 x1 = {__uint_as_float(u.y << 16), __uint_as_float(u.y & 0xffff0000u)};
            f32x2 x2 = {__uint_as_float(u.z << 16), __uint_as_float(u.z & 0xffff0000u)};
            f32x2 x3 = {__uint_as_float(u.w << 16), __uint_as_float(u.w & 0xffff0000u)};
            a0 += vv * x0;
            a1 += vv * x1;
            a2 += vv * x2;
            a3 += vv * x3;
        }
        ushort4 p0, p1;
        p0.x = f2bf(a0.x); p0.y = f2bf(a0.y); p0.z = f2bf(a1.x); p0.w = f2bf(a1.y);
        p1.x = f2bf(a2.x); p1.y = f2bf(a2.y); p1.z = f2bf(a3.x); p1.w = f2bf(a3.y);
        *(ushort4*)(&tile[fi][lane * 8])     = p0;
        *(ushort4*)(&tile[fi][lane * 8 + 4]) = p1;
    }
    __syncthreads();

    // Epilogue: out[b0+r][fbase..fbase+31] = tile[.][r] + bias, coalesced nt.
    const int chunk = tid & 7;                 // 8 f32x4 across 32 f
    const int rbase = tid >> 3;                // 64 rows of b per iter
    float4 bv = ((const float4*)bias)[(fbase >> 2) + chunk];
#pragma unroll
    for (int p = 0; p < 8; ++p) {
        int r = rbase + p * 64;
        f32x4 o;
        o.x = bf2f(tile[chunk * 4 + 0][r]) + bv.x;
        o.y = bf2f(tile[chunk * 4 + 1][r]) + bv.y;
        o.z = bf2f(tile[chunk * 4 + 2][r]) + bv.z;
        o.w = bf2f(tile[chunk * 4 + 3][r]) + bv.w;
        __builtin_nontemporal_store(
            o, (f32x4*)(out + (long)(b0 + r) * NF + fbase + chunk * 4));
    }
}

// ---------- Fallback (R2 structure) if ws too small ----------
__global__ void init_out_kernel(float* __restrict__ out,
                                const float* __restrict__ bias) {
    const int nf4 = NF / 4;
    const long total = (long)BATCH_TOTAL * nf4;
    const float4* b4 = (const float4*)bias;
    float4* o4 = (float4*)out;
    for (long i = (long)blockIdx.x * blockDim.x + threadIdx.x; i < total;
         i += (long)gridDim.x * blockDim.x)
        o4[i] = b4[i & (nf4 - 1)];
}

__global__ void scatter3_kernel(const float* __restrict__ vals,
                                const int* __restrict__ rows,
                                const int* __restrict__ cols,
                                int* __restrict__ cursor,
                                float* __restrict__ sval,
                                int* __restrict__ scol,
                                int* __restrict__ srow, int nnz) {
    int k = blockIdx.x * blockDim.x + threadIdx.x;
    if (k < nnz) {
        int r = rows[k];
        int p = atomicAdd(&cursor[r], 1);
        sval[p] = vals[k];
        scol[p] = cols[k];
        srow[p] = r;
    }
}

#define TILE_B_FB 4
__global__ __launch_bounds__(512, 4)
void spmm_csr_fb_kernel(const float* __restrict__ inputs,
                        const float* __restrict__ sval,
                        const int* __restrict__ scol,
                        const int* __restrict__ srow,
                        float* __restrict__ out, int nnz) {
    __shared__ float in_lds[TILE_B_FB][IND];
    const int tid = threadIdx.x;
    const long b0 = (long)blockIdx.x * TILE_B_FB;
    for (int i = tid; i < IND / 4; i += 512) {
#pragma unroll
        for (int j = 0; j < TILE_B_FB; ++j)
            ((float4*)in_lds[j])[i] = ((const float4*)(inputs + (b0 + j) * IND))[i];
    }
    __syncthreads();
    const int C = (nnz + 511) / 512;
    int k0 = tid * C, k1 = min(k0 + C, nnz);
    if (k0 < k1) {
        int cur = srow[k0];
        float a0 = 0.f, a1 = 0.f, a2 = 0.f, a3 = 0.f;
        for (int k = k0; k < k1; ++k) {
            int r = srow[k];
            float v = sval[k];
            int c = scol[k];
            if (r != cur) {
                atomicAdd(&out[(b0 + 0) * NF + cur], a0);
                atomicAdd(&out[(b0 + 1) * NF + cur], a1);
                atomicAdd(&out[(b0 + 2) * NF + cur], a2);
                atomicAdd(&out[(b0 + 3) * NF + cur], a3);
                a0 = a1 = a2 = a3 = 0.f;
                cur = r;
            }
            a0 += v * in_lds[0][c];
            a1 += v * in_lds[1][c];
            a2 += v * in_lds[2][c];
            a3 += v * in_lds[3][c];
        }
        atomicAdd(&out[(b0 + 0) * NF + cur], a0);
        atomicAdd(&out[(b0 + 1) * NF + cur], a1);
        atomicAdd(&out[(b0 + 2) * NF + cur], a2);
        atomicAdd(&out[(b0 + 3) * NF + cur], a3);
    }
}

extern "C" void kernel_launch(void* const* d_in, const int* in_sizes, int n_in,
                              void* d_out, int out_size, void* d_ws, size_t ws_size,
                              hipStream_t stream) {
    const float* inputs = (const float*)d_in[0];
    const float* vals   = (const float*)d_in[1];
    const int*   rows   = (const int*)d_in[2];
    const int*   cols   = (const int*)d_in[3];
    const float* bias   = (const float*)d_in[4];
    float* out = (float*)d_out;
    const int nnz = in_sizes[1];

    char* ws = (char*)d_ws;
    size_t off = 0;
    int* cnt    = (int*)(ws + off); off += (size_t)NF * 4;
    int* cursor = (int*)(ws + off); off += (size_t)NF * 4;
    int* rptr   = (int*)(ws + off); off += (size_t)NF * 4;
    size_t pairs_off = (off + 15) & ~(size_t)15;
    int2* pairs = (int2*)(ws + pairs_off);
    size_t after_pairs = (pairs_off + (size_t)nnz * 8 + 15) & ~(size_t)15;
    unsigned short* inT = (unsigned short*)(ws + after_pairs);
    size_t need_main = after_pairs + (size_t)IND * BATCH_TOTAL * 2;

    const int eb = (nnz + 255) / 256;

    if (need_main <= ws_size) {
        (void)hipMemsetAsync(cnt, 0, (size_t)NF * 4, stream);
        hist_kernel<<<eb, 256, 0, stream>>>(rows, cnt, nnz);
        scan_kernel<<<1, 1024, 0, stream>>>(cnt, rptr, cursor);
        scatter_pairs_kernel<<<eb, 256, 0, stream>>>(vals, rows, cols, cursor,
                                                     pairs, nnz);
        transpose_kernel<<<(IND / 64) * (BATCH_TOTAL / 64), 256, 0, stream>>>(
            inputs, inT);
        spmm_axpy_kernel<<<(NF / FT) * (BATCH_TOTAL / BT), NT_MAIN, 0, stream>>>(
            inT, pairs, rptr, cnt, bias, out);
    } else {
        int*   srow = (int*)(ws + pairs_off);
        int*   scol = srow + nnz;
        float* sval = (float*)(scol + nnz);
        (void)hipMemsetAsync(cnt, 0, (size_t)NF * 4, stream);
        init_out_kernel<<<2048, 256, 0, stream>>>(out, bias);
        hist_kernel<<<eb, 256, 0, stream>>>(rows, cnt, nnz);
        scan_kernel<<<1, 1024, 0, stream>>>(cnt, rptr, cursor);
        scatter3_kernel<<<eb, 256, 0, stream>>>(vals, rows, cols, cursor,
                                                sval, scol, srow, nnz);
        spmm_csr_fb_kernel<<<BATCH_TOTAL / TILE_B_FB, 512, 0, stream>>>(
            inputs, sval, scol, srow, out, nnz);
    }
}

// Round 9
// 115.527 us; speedup vs baseline: 30.5580x; 1.1938x over previous
//
#include <hip/hip_runtime.h>

// out[b][f] = sum_{k: rows[k]=f} vals[k] * inputs[b][cols[k]] + bias[f]
//
// R9: (a) pairs sorted by (col-half, row); main kernel walks half0 for all
//     its features then half1 (acc in regs across halves) -> instantaneous
//     per-XCD inT working set = 2MB (fits 4MB L2), cutting L2-miss stalls.
//     FT 32->16 so the dual-feature acc fits 8-wave VGPR budget (64).
// (b) setup trimmed: transpose||hist fused in one kernel; 512-thread scan
//     over 8192 counters. 5 launches total.
// Main loop unchanged from R8: 16B/lane bf16 gathers, packed f32x2 FMA.

#define NF 4096
#define IND 4096
#define BATCH_TOTAL 4096
#define FT 16
#define BT 512
#define NT_MAIN 512
#define NTILES ((IND / 64) * (BATCH_TOTAL / 64))   // 4096 transpose tiles

typedef float f32x4 __attribute__((ext_vector_type(4)));
typedef float f32x2 __attribute__((ext_vector_type(2)));

__device__ __forceinline__ float bf2f(unsigned short u) {
    return __uint_as_float(((unsigned int)u) << 16);
}
__device__ __forceinline__ unsigned short f2bf(float x) {
    unsigned int h = __float_as_uint(x);
    h += 0x7fff + ((h >> 16) & 1);   // round-to-nearest-even
    return (unsigned short)(h >> 16);
}

// ---------- F1: fused transpose (blocks 0..NTILES-1) + half-hist ----------
__global__ __launch_bounds__(256)
void fused_transpose_hist(const float* __restrict__ in,
                          unsigned short* __restrict__ outT,
                          const int* __restrict__ rows,
                          const int* __restrict__ cols,
                          int* __restrict__ cnt2, int nnz) {
    if (blockIdx.x < NTILES) {
        __shared__ float t[64][65];
        const int tb = blockIdx.x;
        const int d0 = (tb & 63) * 64;
        const int b0 = (tb >> 6) * 64;
        const int tx4 = threadIdx.x & 15;
        const int ty  = threadIdx.x >> 4;
#pragma unroll
        for (int p = 0; p < 4; ++p) {
            int brow = ty + p * 16;
            float4 v = *(const float4*)(in + (long)(b0 + brow) * IND + d0 + tx4 * 4);
            t[brow][tx4 * 4 + 0] = v.x;
            t[brow][tx4 * 4 + 1] = v.y;
            t[brow][tx4 * 4 + 2] = v.z;
            t[brow][tx4 * 4 + 3] = v.w;
        }
        __syncthreads();
        const int bx4 = threadIdx.x & 15;
        const int dy  = threadIdx.x >> 4;
#pragma unroll
        for (int p = 0; p < 4; ++p) {
            int drow = dy + p * 16;
            ushort4 o;
            o.x = f2bf(t[bx4 * 4 + 0][drow]);
            o.y = f2bf(t[bx4 * 4 + 1][drow]);
            o.z = f2bf(t[bx4 * 4 + 2][drow]);
            o.w = f2bf(t[bx4 * 4 + 3][drow]);
            *(ushort4*)(outT + (long)(d0 + drow) * BATCH_TOTAL + b0 + bx4 * 4) = o;
        }
    } else {
        int k = (blockIdx.x - NTILES) * 256 + threadIdx.x;
        if (k < nnz) {
            int key = ((cols[k] >> 11) << 12) | rows[k];   // half*4096 + row
            atomicAdd(&cnt2[key], 1);
        }
    }
}

// ---------- S1: exclusive scan of 8192 counts -> rptr2 and cursor2 ----------
__global__ __launch_bounds__(512)
void scan8k_kernel(const int* __restrict__ cnt2, int* __restrict__ rptr2,
                   int* __restrict__ cursor2) {
    __shared__ int ts[512];
    const int t = threadIdx.x;
    const int base = t * 16;
    int e[16];
    int tot = 0;
#pragma unroll
    for (int i = 0; i < 16; ++i) { e[i] = cnt2[base + i]; tot += e[i]; }
    ts[t] = tot;
    __syncthreads();
    for (int off = 1; off < 512; off <<= 1) {
        int v = (t >= off) ? ts[t - off] : 0;
        __syncthreads();
        ts[t] += v;
        __syncthreads();
    }
    int run = (t == 0) ? 0 : ts[t - 1];
#pragma unroll
    for (int i = 0; i < 16; ++i) {
        rptr2[base + i] = run;
        cursor2[base + i] = run;
        run += e[i];
    }
}

// ---------- S2: scatter entries sorted by (half, row) ----------
__global__ void scatter_pairs2_kernel(const float* __restrict__ vals,
                                      const int* __restrict__ rows,
                                      const int* __restrict__ cols,
                                      int* __restrict__ cursor2,
                                      int2* __restrict__ pairs, int nnz) {
    int k = blockIdx.x * blockDim.x + threadIdx.x;
    if (k < nnz) {
        int c = cols[k];
        int key = ((c >> 11) << 12) | rows[k];
        int p = atomicAdd(&cursor2[key], 1);
        pairs[p] = make_int2(c, __float_as_int(vals[k]));
    }
}

// ---------- per-segment AXPY walk ----------
__device__ __forceinline__ void walk_seg(const int2* __restrict__ pairs,
                                         int start, int n,
                                         const unsigned short* __restrict__ gbase,
                                         f32x2& a0, f32x2& a1, f32x2& a2, f32x2& a3) {
#pragma unroll 4
    for (int k = 0; k < n; ++k) {
        int2 e = pairs[start + k];                       // uniform scalar
        float v = __int_as_float(e.y);
        f32x2 vv = {v, v};
        uint4 u = *(const uint4*)(gbase + (long)e.x * BATCH_TOTAL);
        f32x2 x0 = {__uint_as_float(u.x << 16), __uint_as_float(u.x & 0xffff0000u)};
        f32x2 x1 = {__uint_as_float(u.y << 16), __uint_as_float(u.y & 0xffff0000u)};
        f32x2 x2 = {__uint_as_float(u.z << 16), __uint_as_float(u.z & 0xffff0000u)};
        f32x2 x3 = {__uint_as_float(u.w << 16), __uint_as_float(u.w & 0xffff0000u)};
        a0 += vv * x0;
        a1 += vv * x1;
        a2 += vv * x2;
        a3 += vv * x3;
    }
}

// ---------- K4: main CSR-AXPY (half-phased, dual-feature per wave) ----------
__global__ __launch_bounds__(NT_MAIN, 8)
void spmm_axpy_kernel(const unsigned short* __restrict__ inT,
                      const int2* __restrict__ pairs,
                      const int* __restrict__ rptr2,
                      const int* __restrict__ cnt2,
                      const float* __restrict__ bias,
                      float* __restrict__ out) {
#pragma clang fp contract(fast)
    __shared__ unsigned short tile[FT][BT + 8];  // 16.6 KB -> 4 blocks/CU

    // XCD-chunked bijective swizzle (nwg = 2048). fblk fastest within a
    // chunk: each XCD's resident blocks sweep fblks of ONE bt-slice, and
    // (via the h-loop below) the same col-half at the same time.
    const int bid = blockIdx.x;
    const int per = gridDim.x >> 3;            // 256
    const int wg = (bid & 7) * per + (bid >> 3);
    const int fblk = wg & (NF / FT - 1);       // 0..255
    const int bt   = wg >> 8;                  // 0..7
    const int b0 = bt * BT;
    const int fbase = fblk * FT;

    const int tid = threadIdx.x;
    const int wid = tid >> 6;                  // 0..7
    const int lane = tid & 63;

    const int fA = fbase + wid;                // features fbase+0..7
    const int fB = fbase + 8 + wid;            // features fbase+8..15

    f32x2 aA0 = {0.f, 0.f}, aA1 = {0.f, 0.f}, aA2 = {0.f, 0.f}, aA3 = {0.f, 0.f};
    f32x2 aB0 = {0.f, 0.f}, aB1 = {0.f, 0.f}, aB2 = {0.f, 0.f}, aB3 = {0.f, 0.f};
    const unsigned short* gbase = inT + b0 + lane * 8;

#pragma unroll
    for (int h = 0; h < 2; ++h) {              // col-half phases (outer!)
        const int oA = h * NF + fA;
        const int sA = __builtin_amdgcn_readfirstlane(rptr2[oA]);
        const int nA = __builtin_amdgcn_readfirstlane(cnt2[oA]);
        walk_seg(pairs, sA, nA, gbase, aA0, aA1, aA2, aA3);
        const int oB = h * NF + fB;
        const int sB = __builtin_amdgcn_readfirstlane(rptr2[oB]);
        const int nB = __builtin_amdgcn_readfirstlane(cnt2[oB]);
        walk_seg(pairs, sB, nB, gbase, aB0, aB1, aB2, aB3);
    }

    ushort4 p0, p1;
    p0.x = f2bf(aA0.x); p0.y = f2bf(aA0.y); p0.z = f2bf(aA1.x); p0.w = f2bf(aA1.y);
    p1.x = f2bf(aA2.x); p1.y = f2bf(aA2.y); p1.z = f2bf(aA3.x); p1.w = f2bf(aA3.y);
    *(ushort4*)(&tile[wid][lane * 8])     = p0;
    *(ushort4*)(&tile[wid][lane * 8 + 4]) = p1;
    p0.x = f2bf(aB0.x); p0.y = f2bf(aB0.y); p0.z = f2bf(aB1.x); p0.w = f2bf(aB1.y);
    p1.x = f2bf(aB2.x); p1.y = f2bf(aB2.y); p1.z = f2bf(aB3.x); p1.w = f2bf(aB3.y);
    *(ushort4*)(&tile[wid + 8][lane * 8])     = p0;
    *(ushort4*)(&tile[wid + 8][lane * 8 + 4]) = p1;
    __syncthreads();

    // Epilogue: out[b0+r][fbase..fbase+15] = tile[.][r] + bias, coalesced nt.
    const int chunk = tid & 3;                 // 4 f32x4 across 16 f
    const int rbase = tid >> 2;                // 128 rows of b per iter
    float4 bv = ((const float4*)bias)[(fbase >> 2) + chunk];
#pragma unroll
    for (int p = 0; p < 4; ++p) {
        int r = rbase + p * 128;
        f32x4 o;
        o.x = bf2f(tile[chunk * 4 + 0][r]) + bv.x;
        o.y = bf2f(tile[chunk * 4 + 1][r]) + bv.y;
        o.z = bf2f(tile[chunk * 4 + 2][r]) + bv.z;
        o.w = bf2f(tile[chunk * 4 + 3][r]) + bv.w;
        __builtin_nontemporal_store(
            o, (f32x4*)(out + (long)(b0 + r) * NF + fbase + chunk * 4));
    }
}

// ---------- Fallback (R2 structure) if ws too small ----------
__global__ void init_out_kernel(float* __restrict__ out,
                                const float* __restrict__ bias) {
    const int nf4 = NF / 4;
    const long total = (long)BATCH_TOTAL * nf4;
    const float4* b4 = (const float4*)bias;
    float4* o4 = (float4*)out;
    for (long i = (long)blockIdx.x * blockDim.x + threadIdx.x; i < total;
         i += (long)gridDim.x * blockDim.x)
        o4[i] = b4[i & (nf4 - 1)];
}

__global__ void hist_kernel(const int* __restrict__ rows,
                            int* __restrict__ cnt, int nnz) {
    int k = blockIdx.x * blockDim.x + threadIdx.x;
    if (k < nnz) atomicAdd(&cnt[rows[k]], 1);
}

__global__ __launch_bounds__(1024)
void scan_kernel(const int* __restrict__ cnt, int* __restrict__ rptr,
                 int* __restrict__ cursor) {
    __shared__ int ts[1024];
    const int t = threadIdx.x;
    const int base = t * 4;
    int e0 = cnt[base], e1 = cnt[base + 1], e2 = cnt[base + 2], e3 = cnt[base + 3];
    ts[t] = e0 + e1 + e2 + e3;
    __syncthreads();
    for (int off = 1; off < 1024; off <<= 1) {
        int v = (t >= off) ? ts[t - off] : 0;
        __syncthreads();
        ts[t] += v;
        __syncthreads();
    }
    int excl = (t == 0) ? 0 : ts[t - 1];
    int p0 = excl, p1 = excl + e0, p2 = p1 + e1, p3 = p2 + e2;
    rptr[base + 0] = p0;   cursor[base + 0] = p0;
    rptr[base + 1] = p1;   cursor[base + 1] = p1;
    rptr[base + 2] = p2;   cursor[base + 2] = p2;
    rptr[base + 3] = p3;   cursor[base + 3] = p3;
}

__global__ void scatter3_kernel(const float* __restrict__ vals,
                                const int* __restrict__ rows,
                                const int* __restrict__ cols,
                                int* __restrict__ cursor,
                                float* __restrict__ sval,
                                int* __restrict__ scol,
                                int* __restrict__ srow, int nnz) {
    int k = blockIdx.x * blockDim.x + threadIdx.x;
    if (k < nnz) {
        int r = rows[k];
        int p = atomicAdd(&cursor[r], 1);
        sval[p] = vals[k];
        scol[p] = cols[k];
        srow[p] = r;
    }
}

#define TILE_B_FB 4
__global__ __launch_bounds__(512, 4)
void spmm_csr_fb_kernel(const float* __restrict__ inputs,
                        const float* __restrict__ sval,
                        const int* __restrict__ scol,
                        const int* __restrict__ srow,
                        float* __restrict__ out, int nnz) {
    __shared__ float in_lds[TILE_B_FB][IND];
    const int tid = threadIdx.x;
    const long b0 = (long)blockIdx.x * TILE_B_FB;
    for (int i = tid; i < IND / 4; i += 512) {
#pragma unroll
        for (int j = 0; j < TILE_B_FB; ++j)
            ((float4*)in_lds[j])[i] = ((const float4*)(inputs + (b0 + j) * IND))[i];
    }
    __syncthreads();
    const int C = (nnz + 511) / 512;
    int k0 = tid * C, k1 = min(k0 + C, nnz);
    if (k0 < k1) {
        int cur = srow[k0];
        float a0 = 0.f, a1 = 0.f, a2 = 0.f, a3 = 0.f;
        for (int k = k0; k < k1; ++k) {
            int r = srow[k];
            float v = sval[k];
            int c = scol[k];
            if (r != cur) {
                atomicAdd(&out[(b0 + 0) * NF + cur], a0);
                atomicAdd(&out[(b0 + 1) * NF + cur], a1);
                atomicAdd(&out[(b0 + 2) * NF + cur], a2);
                atomicAdd(&out[(b0 + 3) * NF + cur], a3);
                a0 = a1 = a2 = a3 = 0.f;
                cur = r;
            }
            a0 += v * in_lds[0][c];
            a1 += v * in_lds[1][c];
            a2 += v * in_lds[2][c];
            a3 += v * in_lds[3][c];
        }
        atomicAdd(&out[(b0 + 0) * NF + cur], a0);
        atomicAdd(&out[(b0 + 1) * NF + cur], a1);
        atomicAdd(&out[(b0 + 2) * NF + cur], a2);
        atomicAdd(&out[(b0 + 3) * NF + cur], a3);
    }
}

extern "C" void kernel_launch(void* const* d_in, const int* in_sizes, int n_in,
                              void* d_out, int out_size, void* d_ws, size_t ws_size,
                              hipStream_t stream) {
    const float* inputs = (const float*)d_in[0];
    const float* vals   = (const float*)d_in[1];
    const int*   rows   = (const int*)d_in[2];
    const int*   cols   = (const int*)d_in[3];
    const float* bias   = (const float*)d_in[4];
    float* out = (float*)d_out;
    const int nnz = in_sizes[1];

    char* ws = (char*)d_ws;
    size_t off = 0;
    int* cnt2    = (int*)(ws + off); off += (size_t)2 * NF * 4;   // 32 KB
    int* cursor2 = (int*)(ws + off); off += (size_t)2 * NF * 4;   // 32 KB
    int* rptr2   = (int*)(ws + off); off += (size_t)2 * NF * 4;   // 32 KB
    size_t pairs_off = (off + 15) & ~(size_t)15;
    int2* pairs = (int2*)(ws + pairs_off);
    size_t after_pairs = (pairs_off + (size_t)nnz * 8 + 15) & ~(size_t)15;
    unsigned short* inT = (unsigned short*)(ws + after_pairs);
    size_t need_main = after_pairs + (size_t)IND * BATCH_TOTAL * 2;

    const int eb = (nnz + 255) / 256;

    if (need_main <= ws_size) {
        (void)hipMemsetAsync(cnt2, 0, (size_t)2 * NF * 4, stream);
        fused_transpose_hist<<<NTILES + eb, 256, 0, stream>>>(
            inputs, inT, rows, cols, cnt2, nnz);
        scan8k_kernel<<<1, 512, 0, stream>>>(cnt2, rptr2, cursor2);
        scatter_pairs2_kernel<<<eb, 256, 0, stream>>>(vals, rows, cols, cursor2,
                                                      pairs, nnz);
        spmm_axpy_kernel<<<(NF / FT) * (BATCH_TOTAL / BT), NT_MAIN, 0, stream>>>(
            inT, pairs, rptr2, cnt2, bias, out);
    } else {
        // Fallback: R2 structure (needs ~2.1 MB of ws).
        int* cnt    = cnt2;
        int* cursor = cursor2;
        int* rptr   = rptr2;
        int*   srow = (int*)(ws + pairs_off);
        int*   scol = srow + nnz;
        float* sval = (float*)(scol + nnz);
        (void)hipMemsetAsync(cnt, 0, (size_t)NF * 4, stream);
        init_out_kernel<<<2048, 256, 0, stream>>>(out, bias);
        hist_kernel<<<eb, 256, 0, stream>>>(rows, cnt, nnz);
        scan_kernel<<<1, 1024, 0, stream>>>(cnt, rptr, cursor);
        scatter3_kernel<<<eb, 256, 0, stream>>>(vals, rows, cols, cursor,
                                                sval, scol, srow, nnz);
        spmm_csr_fb_kernel<<<BATCH_TOTAL / TILE_B_FB, 512, 0, stream>>>(
            inputs, sval, scol, srow, out, nnz);
    }
}